// Round 4
// baseline (1528.497 us; speedup 1.0000x reference)
//
#include <hip/hip_runtime.h>
#include <hip/hip_cooperative_groups.h>
#include <stdint.h>

namespace cg = cooperative_groups;

#define NB 4096            // batch rows
#define NC 8192            // classes / text rows
#define ND 512             // feature dim
#define INV_TEMP (1.0f/0.07f)

typedef float  f32x4 __attribute__((ext_vector_type(4)));
typedef unsigned int u32x4 __attribute__((ext_vector_type(4)));

__device__ __forceinline__ unsigned short f2bf(float f) {
    unsigned int u = __float_as_uint(f);
    u += 0x7fffu + ((u >> 16) & 1u);          // RNE
    return (unsigned short)(u >> 16);
}
__device__ __forceinline__ float bflo(unsigned int u) {   // low 16 bits -> f32
    return __uint_as_float(u << 16);
}
__device__ __forceinline__ float bfhi(unsigned int u) {   // high 16 bits -> f32
    return __uint_as_float(u & 0xFFFF0000u);
}

// ---------------- prep: F/T -> bf16 convert + init state, ONE dispatch ----------------
// blocks [0, 6144): cvt (F first 2048, T next 4096); block 6144: init scalars/vectors.
__global__ __launch_bounds__(256) void k_prep(const float4* __restrict__ F4,
                                              const float4* __restrict__ T4,
                                              unsigned short* __restrict__ Fb,
                                              unsigned short* __restrict__ Tb,
                                              const int* __restrict__ idx,
                                              float* __restrict__ colsum,
                                              float* __restrict__ rv,
                                              float* __restrict__ scal) {
    const int tid = threadIdx.x;
    const int b = blockIdx.x;
    if (b < 6144) {
        const int i  = b * 256 + tid;
        const int nF = NB * ND / 4;
        const float4 v = (i < nF) ? F4[i] : T4[i - nF];
        union { unsigned short h[4]; uint2 u; } p;
        p.h[0] = f2bf(v.x); p.h[1] = f2bf(v.y); p.h[2] = f2bf(v.z); p.h[3] = f2bf(v.w);
        if (i < nF) ((uint2*)Fb)[i] = p.u;
        else        ((uint2*)Tb)[i - nF] = p.u;
        return;
    }
    // init block
    int cnt = 0;
    for (int q = tid; q < NB; q += 256) {
        colsum[q] = 0.f;
        rv[q] = 1.f;
        cnt += (idx[q] == 1) ? 1 : 0;
    }
#pragma unroll
    for (int off = 1; off < 64; off <<= 1) cnt += __shfl_xor(cnt, off);
    __shared__ int redi[4];
    if ((tid & 63) == 0) redi[tid >> 6] = cnt;
    __syncthreads();
    if (tid == 0) {
        const int c1 = redi[0] + redi[1] + redi[2] + redi[3];
        const float m = (float)c1 + 0.1f * (float)(NB - c1);
        scal[0] = m;                                   // m
        scal[1] = 0.f;                                 // asl accumulator
        scal[2] = 0.f;                                 // multiclass accumulator
        scal[4] = m;                                   // S[0] = m  (=> SC_0 = 1)
        scal[5] = 0.f; scal[6] = 0.f; scal[7] = 0.f; scal[8] = 0.f; scal[9] = 0.f;
        ((unsigned int*)scal)[10] = 0u;                // rowfinal finisher counter
    }
}

// ---------------- legacy init (fallback path) ----------------
__global__ __launch_bounds__(1024) void k_init(const int* __restrict__ idx,
                                               float* __restrict__ colsum,
                                               float* __restrict__ rv,
                                               float* __restrict__ scal) {
    __shared__ int red[1024];
    const int tid = threadIdx.x;
    int cnt = 0;
    for (int q = tid; q < NB; q += 1024) {
        colsum[q] = 0.f;
        rv[q] = 1.f;
        cnt += (idx[q] == 1) ? 1 : 0;
    }
    red[tid] = cnt; __syncthreads();
    for (int s = 512; s > 0; s >>= 1) {
        if (tid < s) red[tid] += red[tid + s];
        __syncthreads();
    }
    if (tid == 0) {
        const int c1 = red[0];
        scal[0] = (float)c1 + 0.1f * (float)(NB - c1);
        scal[1] = 0.f;
        scal[2] = 0.f;
    }
}

// ---------------- legacy cvt (fallback path) ----------------
__global__ __launch_bounds__(256) void k_cvt(const float4* __restrict__ src,
                                             unsigned short* __restrict__ dst, int n4) {
    const int i = blockIdx.x * 256 + threadIdx.x;
    if (i >= n4) return;
    const float4 v = src[i];
    union { unsigned short h[4]; uint2 u; } p;
    p.h[0] = f2bf(v.x); p.h[1] = f2bf(v.y); p.h[2] = f2bf(v.z); p.h[3] = f2bf(v.w);
    ((uint2*)dst)[i] = p.u;
}

// ---------------- GEMM: sim = (F @ T^T) * (1/0.07), bf16 MFMA ----------------
// 128x128 tile, BK=64, 4 waves (2x2), 16x16x32 MFMA, XOR-swizzled LDS,
// global_load_lds width 16 with pre-swizzled global source.
// fused=1: write masked coco/cifar directly (no sim buffer, no mask pass).
__global__ __launch_bounds__(256) void k_gemm(const unsigned short* __restrict__ Fb,
                                              const unsigned short* __restrict__ Tb,
                                              const int* __restrict__ idx,
                                              float* __restrict__ sim,
                                              float* __restrict__ coco,
                                              float* __restrict__ cifar,
                                              int fused) {
    __shared__ unsigned short lA[128 * 64];   // 16 KB, [row][k] bf16, swizzled
    __shared__ unsigned short lB[128 * 64];   // 16 KB
    const int tid  = threadIdx.x;
    const int lane = tid & 63;
    const int wid  = tid >> 6;                // 0..3
    const int wm = wid >> 1, wn = wid & 1;    // 2x2 wave grid, 64x64 each
    const int brow = blockIdx.y * 128;
    const int bcol = blockIdx.x * 128;

    f32x4 acc[4][4] = {};

    for (int kt = 0; kt < ND / 64; ++kt) {
        if (kt) __syncthreads();
#pragma unroll
        for (int c = 0; c < 4; ++c) {
            const int ch  = c * 4 + wid;
            const int o   = ch * 1024 + lane * 16;   // linear LDS byte
            const int row = o >> 7;                  // 128 B per row
            const int kbu = (o & 127) ^ ((row & 7) << 4); // inverse-swizzled source
            const unsigned short* gA = Fb + ((size_t)(brow + row) << 9) + (kt << 5)*2 + (kbu >> 1);
            __builtin_amdgcn_global_load_lds(
                (const __attribute__((address_space(1))) unsigned int*)gA,
                (__attribute__((address_space(3))) unsigned int*)((char*)lA + ch * 1024),
                16, 0, 0);
            const unsigned short* gB = Tb + ((size_t)(bcol + row) << 9) + (kt << 5)*2 + (kbu >> 1);
            __builtin_amdgcn_global_load_lds(
                (const __attribute__((address_space(1))) unsigned int*)gB,
                (__attribute__((address_space(3))) unsigned int*)((char*)lB + ch * 1024),
                16, 0, 0);
        }
        __syncthreads();
#pragma unroll
        for (int ks = 0; ks < 2; ++ks) {
            u32x4 af[4], bfr[4];
#pragma unroll
            for (int mi = 0; mi < 4; ++mi) {
                const int row  = wm * 64 + mi * 16 + (lane & 15);
                const int kb   = ks * 64 + ((lane >> 4) << 4);
                const int addr = row * 128 + (kb ^ ((row & 7) << 4));
                af[mi] = *(const u32x4*)((const char*)lA + addr);
            }
#pragma unroll
            for (int ni = 0; ni < 4; ++ni) {
                const int row  = wn * 64 + ni * 16 + (lane & 15);
                const int kb   = ks * 64 + ((lane >> 4) << 4);
                const int addr = row * 128 + (kb ^ ((row & 7) << 4));
                bfr[ni] = *(const u32x4*)((const char*)lB + addr);
            }
#pragma unroll
            for (int mi = 0; mi < 4; ++mi)
#pragma unroll
                for (int ni = 0; ni < 4; ++ni)
                    asm("v_mfma_f32_16x16x32_bf16 %0, %1, %2, %0"
                        : "+v"(acc[mi][ni]) : "v"(af[mi]), "v"(bfr[ni]));
        }
    }
    asm volatile("s_nop 7\n\ts_nop 7\n\ts_nop 7" ::);   // MFMA->VALU hazard fence
    if (fused) {
#pragma unroll
        for (int mi = 0; mi < 4; ++mi) {
            const int rb = brow + wm * 64 + mi * 16 + ((lane >> 4) << 2);
            int fl[4];
#pragma unroll
            for (int rr = 0; rr < 4; ++rr) fl[rr] = (idx[rb + rr] == 1);
#pragma unroll
            for (int ni = 0; ni < 4; ++ni) {
                const int col = bcol + wn * 64 + ni * 16 + (lane & 15);
#pragma unroll
                for (int rr = 0; rr < 4; ++rr) {
                    const float s = acc[mi][ni][rr] * INV_TEMP;
                    const size_t o = (size_t)(rb + rr) * NC + col;
                    coco[o]  = fl[rr] ? 0.0f : s;
                    cifar[o] = fl[rr] ? s : 0.0f;
                }
            }
        }
    } else {
#pragma unroll
        for (int mi = 0; mi < 4; ++mi) {
            const int rb = brow + wm * 64 + mi * 16 + ((lane >> 4) << 2);
#pragma unroll
            for (int ni = 0; ni < 4; ++ni) {
                const int col = bcol + wn * 64 + ni * 16 + (lane & 15);
#pragma unroll
                for (int rr = 0; rr < 4; ++rr)
                    sim[(size_t)(rb + rr) * NC + col] = acc[mi][ni][rr] * INV_TEMP;
            }
        }
    }
}

// ---------------- per-row stats + ASL loss (one block per row) ----------------
__global__ __launch_bounds__(256) void k_stats(const float* __restrict__ pc,
                                               const float* __restrict__ pf,
                                               const int* __restrict__ idx,
                                               const float* __restrict__ tgt,
                                               unsigned short* __restrict__ Ebf,
                                               float* __restrict__ rowsum0,
                                               float* __restrict__ simdiag,
                                               float* __restrict__ Arow,
                                               float* __restrict__ Tsumv,
                                               float* __restrict__ rowmx,
                                               float* __restrict__ rowmn,
                                               float* __restrict__ scal) {
    const int i = blockIdx.x, tid = threadIdx.x;
    const float* srow = ((idx[i] == 1) ? pf : pc) + (size_t)i * NC;
    const float* trow = tgt + (size_t)i * NC;
    unsigned short* erow = Ebf ? (Ebf + (size_t)i * NC) : nullptr;
    float rs = 0.f, a = 0.f, ts = 0.f, ls = 0.f;
    float mx = -3.4e38f, mn = 3.4e38f;
    for (int c = tid * 4; c < NC; c += 1024) {
        const float s0 = srow[c], s1 = srow[c+1], s2 = srow[c+2], s3 = srow[c+3];
        const float4 t4 = *(const float4*)(trow + c);
        const float t0 = t4.x, t1 = t4.y, t2 = t4.z, t3 = t4.w;
        if ((unsigned)(i - c) < 4u)
            simdiag[i] = (i == c) ? s0 : ((i == c+1) ? s1 : ((i == c+2) ? s2 : s3));
        float e0, e1, e2, e3;
#define ASL(sv, tv, ev) { \
        ev = __expf(sv); \
        rs += ev; a += (tv) * ev; ts += (tv); \
        mx = fmaxf(mx, (sv)); mn = fminf(mn, (sv)); \
        const float inv = __builtin_amdgcn_rcpf(1.0f + ev); \
        const float xsp = ev * inv; \
        const float xsn = fminf(1.05f - xsp, 1.0f); \
        const float lp  = __logf(xsp); \
        const float ln  = __logf(xsn); \
        const float pt  = xsn + (tv) * (xsp - xsn); \
        const float g   = 4.0f - 3.0f * (tv); \
        const float pw  = __builtin_amdgcn_exp2f(g * __builtin_amdgcn_logf(1.0f - pt)); \
        ls += (ln + (tv) * (lp - ln)) * pw; }
        ASL(s0, t0, e0) ASL(s1, t1, e1) ASL(s2, t2, e2) ASL(s3, t3, e3)
#undef ASL
        if (erow) {
            uint2 w;
            w.x = (unsigned)f2bf(e0) | ((unsigned)f2bf(e1) << 16);
            w.y = (unsigned)f2bf(e2) | ((unsigned)f2bf(e3) << 16);
            *(uint2*)(erow + c) = w;
        }
    }
#pragma unroll
    for (int off = 1; off < 64; off <<= 1) {
        rs += __shfl_xor(rs, off);
        a  += __shfl_xor(a , off);
        ts += __shfl_xor(ts, off);
        ls += __shfl_xor(ls, off);
        mx = fmaxf(mx, __shfl_xor(mx, off));
        mn = fminf(mn, __shfl_xor(mn, off));
    }
    __shared__ float red[4][6];
    if ((tid & 63) == 0) {
        const int w = tid >> 6;
        red[w][0] = rs; red[w][1] = a; red[w][2] = ts;
        red[w][3] = ls; red[w][4] = mx; red[w][5] = mn;
    }
    __syncthreads();
    if (tid == 0) {
        rowsum0[i] = red[0][0] + red[1][0] + red[2][0] + red[3][0];
        Arow[i]    = red[0][1] + red[1][1] + red[2][1] + red[3][1];
        Tsumv[i]   = red[0][2] + red[1][2] + red[2][2] + red[3][2];
        atomicAdd(&scal[1], red[0][3] + red[1][3] + red[2][3] + red[3][3]);
        rowmx[i] = fmaxf(fmaxf(red[0][4], red[1][4]), fmaxf(red[2][4], red[3][4]));
        rowmn[i] = fminf(fminf(red[0][5], red[1][5]), fminf(red[2][5], red[3][5]));
    }
}

// ---------------- ALL 5 Sinkhorn iterations in ONE cooperative dispatch ----------------
// 1024 blocks x 256 thr, 4 blocks/CU co-resident. rv[] kept UNSCALED; true r =
// (m/S[t]) * rv. The m/P.sum() normalization cancels the running scale, so only
// the scalar chain S[0..5] (scal[4..9]) carries it. Per iteration:
//   (a) unscaled colsum atomics over Ebf[:, :NB]; grid.sync();
//   (b) blocks 0..15 update rv, accumulate S[t+1], reset colsum; grid.sync();
// Final phase scales rv by m/S[5] so k_rowfinal sees the true r.
__global__ __launch_bounds__(256, 4) void k_sinkhorn(const unsigned short* __restrict__ Ebf,
                                                     float* __restrict__ rv,
                                                     float* __restrict__ colsum,
                                                     const float* __restrict__ simdiag,
                                                     const float* __restrict__ rowsum0,
                                                     float* __restrict__ scal) {
    cg::grid_group grid = cg::this_grid();
    const int tid = threadIdx.x;
    const int bid = blockIdx.x;                 // 0..1023
    const int j0  = (bid & 3) * 1024 + tid * 4; // column slice (4 col-groups)
    const int i0  = (bid >> 2) * 16;            // row slice (256 row-groups x 16 rows)
    float* S = scal + 4;
    const float m = scal[0];
    __shared__ float red[4];
    for (int it = 0; it < 5; ++it) {
        float a0 = 0.f, a1 = 0.f, a2 = 0.f, a3 = 0.f;
        for (int i = i0; i < i0 + 16; ++i) {
            const uint2 u = *(const uint2*)(Ebf + (size_t)i * NC + j0);
            const float r = rv[i];
            a0 += bflo(u.x) * r;
            a1 += bfhi(u.x) * r;
            a2 += bflo(u.y) * r;
            a3 += bfhi(u.y) * r;
        }
        atomicAdd(&colsum[j0    ], a0);
        atomicAdd(&colsum[j0 + 1], a1);
        atomicAdd(&colsum[j0 + 2], a2);
        atomicAdd(&colsum[j0 + 3], a3);
        grid.sync();
        if (bid < 16) {
            const int i = bid * 256 + tid;
            const float SC = m / atomicAdd(&S[it], 0.0f);     // scale: true r = SC*rv
            const float cu = atomicAdd(&colsum[i], 0.0f);     // L2-coherent read
            const float d  = fminf(simdiag[i] / (SC * cu), 1.0f);
            const float rn = rv[i] * d;                       // new unscaled r
            rv[i] = rn;
            colsum[i] = 0.f;                                  // reset for next iter
            float part = rn * rowsum0[i];
#pragma unroll
            for (int off = 1; off < 64; off <<= 1) part += __shfl_xor(part, off);
            if ((tid & 63) == 0) red[tid >> 6] = part;
            __syncthreads();
            if (tid == 0) atomicAdd(&S[it + 1], red[0] + red[1] + red[2] + red[3]);
        }
        grid.sync();
    }
    if (bid < 16) {                                           // finalize: true r
        const int i = bid * 256 + tid;
        rv[i] *= m / atomicAdd(&S[5], 0.0f);
    }
}

// ---------------- logsumexp(P row) + multiclass + final scalars (finisher) ----------------
__global__ __launch_bounds__(256) void k_rowfinal_e2(const unsigned short* __restrict__ Ebf,
                                                     const float* __restrict__ rv,
                                                     const float* __restrict__ Arow,
                                                     const float* __restrict__ Tsumv,
                                                     const float* __restrict__ rowmx,
                                                     const float* __restrict__ rowmn,
                                                     float* __restrict__ scal,
                                                     float* __restrict__ out) {
    const int i = blockIdx.x, tid = threadIdx.x;
    const float ri = rv[i];
    const unsigned short* erow = Ebf + (size_t)i * NC;
    const float M = ri * __expf((ri >= 0.f) ? rowmx[i] : rowmn[i]);
    float se = 0.f;
    for (int c = tid * 8; c < NC; c += 2048) {
        const uint4 u = *(const uint4*)(erow + c);
        se += __expf(ri * bflo(u.x) - M);
        se += __expf(ri * bfhi(u.x) - M);
        se += __expf(ri * bflo(u.y) - M);
        se += __expf(ri * bfhi(u.y) - M);
        se += __expf(ri * bflo(u.z) - M);
        se += __expf(ri * bfhi(u.z) - M);
        se += __expf(ri * bflo(u.w) - M);
        se += __expf(ri * bfhi(u.w) - M);
    }
#pragma unroll
    for (int off = 1; off < 64; off <<= 1) se += __shfl_xor(se, off);
    __shared__ float red[4];
    if ((tid & 63) == 0) red[tid >> 6] = se;
    __syncthreads();
    if (tid == 0) {
        const float L = M + __logf(red[0] + red[1] + red[2] + red[3]);
        atomicAdd(&scal[2], Tsumv[i] * L - ri * Arow[i]);
        __threadfence();
        if (atomicAdd(((unsigned int*)scal) + 10, 1u) == (unsigned int)(NB - 1)) {
            const float mc = atomicAdd(&scal[2], 0.0f) / (float)NB;
            const float ml = -atomicAdd(&scal[1], 0.0f);
            out[0] = mc + ml;
            out[1] = mc;
            out[2] = ml;
        }
    }
}

// ---------------- fallback kernels (no E buffer path) ----------------
__global__ __launch_bounds__(256) void k_colsum(const float* __restrict__ pc,
                                                const float* __restrict__ pf,
                                                const int* __restrict__ idx,
                                                const float* __restrict__ rv,
                                                float* __restrict__ colsum) {
    const int j  = (blockIdx.x * 256 + threadIdx.x) * 4;
    const int i0 = blockIdx.y * 32;
    float a0 = 0.f, a1 = 0.f, a2 = 0.f, a3 = 0.f;
    for (int i = i0; i < i0 + 32; ++i) {
        const float* row = ((idx[i] == 1) ? pf : pc) + (size_t)i * NC;
        const float r = rv[i];
        a0 += __expf(row[j    ]) * r;
        a1 += __expf(row[j + 1]) * r;
        a2 += __expf(row[j + 2]) * r;
        a3 += __expf(row[j + 3]) * r;
    }
    atomicAdd(&colsum[j    ], a0);
    atomicAdd(&colsum[j + 1], a1);
    atomicAdd(&colsum[j + 2], a2);
    atomicAdd(&colsum[j + 3], a3);
}

__global__ __launch_bounds__(1024) void k_update(const float* __restrict__ simdiag,
                                                 float* __restrict__ colsum,
                                                 const float* __restrict__ rowsum0,
                                                 float* __restrict__ rv,
                                                 const float* __restrict__ scal) {
    __shared__ float red[1024];
    const int tid = threadIdx.x;
    float part = 0.f;
    float rl[4];
#pragma unroll
    for (int q = 0; q < 4; ++q) {
        const int i = tid + q * 1024;
        const float d  = fminf(simdiag[i] / colsum[i], 1.0f);
        const float rn = rv[i] * d;
        rl[q] = rn;
        part += rn * rowsum0[i];
        colsum[i] = 0.f;
    }
    red[tid] = part; __syncthreads();
    for (int s = 512; s > 0; s >>= 1) {
        if (tid < s) red[tid] += red[tid + s];
        __syncthreads();
    }
    const float sc = scal[0] / red[0];
#pragma unroll
    for (int q = 0; q < 4; ++q) rv[tid + q * 1024] = rl[q] * sc;
}

__global__ __launch_bounds__(256) void k_rowfinal(const float* __restrict__ pc,
                                                  const float* __restrict__ pf,
                                                  const int* __restrict__ idx,
                                                  const float* __restrict__ rv,
                                                  const float* __restrict__ Arow,
                                                  const float* __restrict__ Tsumv,
                                                  const float* __restrict__ rowmx,
                                                  const float* __restrict__ rowmn,
                                                  float* __restrict__ scal) {
    const int i = blockIdx.x, tid = threadIdx.x;
    const float ri = rv[i];
    const float* srow = ((idx[i] == 1) ? pf : pc) + (size_t)i * NC;
    const float M = ri * __expf((ri >= 0.f) ? rowmx[i] : rowmn[i]);
    float se = 0.f;
    for (int c = tid * 4; c < NC; c += 1024) {
        se += __expf(ri * __expf(srow[c    ]) - M);
        se += __expf(ri * __expf(srow[c + 1]) - M);
        se += __expf(ri * __expf(srow[c + 2]) - M);
        se += __expf(ri * __expf(srow[c + 3]) - M);
    }
#pragma unroll
    for (int off = 1; off < 64; off <<= 1) se += __shfl_xor(se, off);
    __shared__ float red[4];
    if ((tid & 63) == 0) red[tid >> 6] = se;
    __syncthreads();
    if (tid == 0) {
        const float L = M + __logf(red[0] + red[1] + red[2] + red[3]);
        atomicAdd(&scal[2], Tsumv[i] * L - ri * Arow[i]);
    }
}

__global__ void k_scalars(const float* __restrict__ scal, float* __restrict__ out) {
    if (threadIdx.x == 0) {
        const float mc = scal[2] / (float)NB;
        const float ml = -scal[1];
        out[0] = mc + ml;
        out[1] = mc;
        out[2] = ml;
    }
}

__global__ __launch_bounds__(256) void k_mask(const float* sim, const int* idx,
                                              float* coco, float* cifar) {
    const int i = blockIdx.y;
    const int c = blockIdx.x * 256 + threadIdx.x;
    const size_t o = (size_t)i * NC + c;
    const float s = sim[o];
    const bool isCifar = (idx[i] == 1);
    coco[o]  = isCifar ? 0.0f : s;
    cifar[o] = isCifar ? s : 0.0f;
}

extern "C" void kernel_launch(void* const* d_in, const int* in_sizes, int n_in,
                              void* d_out, int out_size, void* d_ws, size_t ws_size,
                              hipStream_t stream) {
    const float* F   = (const float*)d_in[0];   // [4096,512]
    const float* T   = (const float*)d_in[1];   // [8192,512]
    const float* tgt = (const float*)d_in[2];   // [4096,8192]
    const int*   idx = (const int*)d_in[3];     // [4096]

    float* out   = (float*)d_out;
    float* coco  = out + 3;
    float* cifar = coco + (size_t)NB * NC;

    const size_t FbBytes    = (size_t)NB * ND * 2;      // 4 MB
    const size_t TbBytes    = (size_t)NC * ND * 2;      // 8 MB
    const size_t EBytes     = (size_t)NB * NC * 2;      // 67 MB
    const size_t smallBytes = 10 * (size_t)NB * 4 + 1024;

    const bool fused = (d_ws != nullptr) &&
                       (ws_size >= FbBytes + TbBytes + smallBytes + 512);
    const bool hasE  = (d_ws != nullptr) &&
                       (ws_size >= FbBytes + TbBytes + EBytes + smallBytes + 512);
    unsigned short *Fb, *Tb, *Ebf = nullptr;
    float *sm, *sim;
    if (fused) {
        Fb  = (unsigned short*)d_ws;
        Tb  = (unsigned short*)((char*)d_ws + FbBytes);
        char* p = (char*)d_ws + FbBytes + TbBytes;
        if (hasE) { Ebf = (unsigned short*)p; p += EBytes; }
        sm  = (float*)p;
        sim = nullptr;
    } else {
        sim = cifar;
        char* base = (char*)(((uintptr_t)(void*)coco + 255) & ~(uintptr_t)255);
        Fb  = (unsigned short*)base;
        Tb  = (unsigned short*)(base + FbBytes);
        sm  = (float*)(base + FbBytes + TbBytes);
    }
    float* colsum  = sm;
    float* rv      = sm + NB;
    float* rowsum0 = sm + 2 * NB;
    float* simdiag = sm + 3 * NB;
    float* Arow    = sm + 4 * NB;
    float* Tsumv   = sm + 5 * NB;
    float* rowmx   = sm + 6 * NB;
    float* rowmn   = sm + 7 * NB;
    float* scal    = sm + 8 * NB;

    if (hasE) {
        // ---- 5-dispatch path ----
        k_prep<<<6145, 256, 0, stream>>>((const float4*)F, (const float4*)T, Fb, Tb,
                                         idx, colsum, rv, scal);
        k_gemm<<<dim3(NC / 128, NB / 128), 256, 0, stream>>>(Fb, Tb, idx, nullptr,
                                                             coco, cifar, 1);
        k_stats<<<NB, 256, 0, stream>>>(coco, cifar, idx, tgt, Ebf, rowsum0, simdiag,
                                        Arow, Tsumv, rowmx, rowmn, scal);
        {
            const unsigned short* aE = Ebf;
            float* arv = rv; float* acs = colsum;
            const float* asd = simdiag; const float* ars = rowsum0;
            float* asc = scal;
            void* args[] = { (void*)&aE, (void*)&arv, (void*)&acs,
                             (void*)&asd, (void*)&ars, (void*)&asc };
            hipLaunchCooperativeKernel((const void*)k_sinkhorn, dim3(1024), dim3(256),
                                       args, 0, stream);
        }
        k_rowfinal_e2<<<NB, 256, 0, stream>>>(Ebf, rv, Arow, Tsumv, rowmx, rowmn,
                                              scal, out);
        return;
    }

    // ---- fallback path (no E buffer) ----
    const float* pc = fused ? coco  : sim;
    const float* pf = fused ? cifar : sim;

    k_init<<<1, 1024, 0, stream>>>(idx, colsum, rv, scal);
    k_cvt<<<(NB * ND / 4) / 256, 256, 0, stream>>>((const float4*)F, Fb, NB * ND / 4);
    k_cvt<<<(NC * ND / 4) / 256, 256, 0, stream>>>((const float4*)T, Tb, NC * ND / 4);
    k_gemm<<<dim3(NC / 128, NB / 128), 256, 0, stream>>>(Fb, Tb, idx, sim, coco, cifar,
                                                         fused ? 1 : 0);
    k_stats<<<NB, 256, 0, stream>>>(pc, pf, idx, tgt, nullptr, rowsum0, simdiag, Arow, Tsumv,
                                    rowmx, rowmn, scal);
    for (int it = 0; it < 5; ++it) {
        k_colsum<<<dim3(NB / 1024, 128), 256, 0, stream>>>(pc, pf, idx, rv, colsum);
        k_update<<<1, 1024, 0, stream>>>(simdiag, colsum, rowsum0, rv, scal);
    }
    k_rowfinal<<<NB, 256, 0, stream>>>(pc, pf, idx, rv, Arow, Tsumv, rowmx, rowmn, scal);
    k_scalars<<<1, 64, 0, stream>>>(scal, out);
    if (!fused) k_mask<<<dim3(NC / 256, NB), 256, 0, stream>>>(sim, idx, coco, cifar);
}

// Round 5
// 402.818 us; speedup vs baseline: 3.7945x; 3.7945x over previous
//
#include <hip/hip_runtime.h>
#include <stdint.h>

#define NB 4096            // batch rows
#define NC 8192            // classes / text rows
#define ND 512             // feature dim
#define INV_TEMP (1.0f/0.07f)

typedef float  f32x4 __attribute__((ext_vector_type(4)));
typedef unsigned int u32x4 __attribute__((ext_vector_type(4)));

__device__ __forceinline__ unsigned short f2bf(float f) {
    unsigned int u = __float_as_uint(f);
    u += 0x7fffu + ((u >> 16) & 1u);          // RNE
    return (unsigned short)(u >> 16);
}
__device__ __forceinline__ float bflo(unsigned int u) {   // low 16 bits -> f32
    return __uint_as_float(u << 16);
}
__device__ __forceinline__ float bfhi(unsigned int u) {   // high 16 bits -> f32
    return __uint_as_float(u & 0xFFFF0000u);
}

// ---------------- prep: F/T -> bf16 convert + init state, ONE dispatch ----------------
// blocks [0, 6144): cvt (F first 2048, T next 4096); block 6144: init scalars/vectors.
// scal layout: [0]=m  [1]=asl acc  [2]=mc acc  [4..8]=c(0..4) scale chain
//              u32[10]=rowfinal finisher counter
__global__ __launch_bounds__(256) void k_prep(const float4* __restrict__ F4,
                                              const float4* __restrict__ T4,
                                              unsigned short* __restrict__ Fb,
                                              unsigned short* __restrict__ Tb,
                                              const int* __restrict__ idx,
                                              float* __restrict__ csum,   // 5*NB slots
                                              float* __restrict__ uA,     // u(0)=1
                                              float* __restrict__ scal) {
    const int tid = threadIdx.x;
    const int b = blockIdx.x;
    if (b < 6144) {
        const int i  = b * 256 + tid;
        const int nF = NB * ND / 4;
        const float4 v = (i < nF) ? F4[i] : T4[i - nF];
        union { unsigned short h[4]; uint2 u; } p;
        p.h[0] = f2bf(v.x); p.h[1] = f2bf(v.y); p.h[2] = f2bf(v.z); p.h[3] = f2bf(v.w);
        if (i < nF) ((uint2*)Fb)[i] = p.u;
        else        ((uint2*)Tb)[i - nF] = p.u;
        return;
    }
    // init block
    for (int q = tid; q < 5 * NB; q += 256) csum[q] = 0.f;
    int cnt = 0;
    for (int q = tid; q < NB; q += 256) {
        uA[q] = 1.f;
        cnt += (idx[q] == 1) ? 1 : 0;
    }
#pragma unroll
    for (int off = 1; off < 64; off <<= 1) cnt += __shfl_xor(cnt, off);
    __shared__ int redi[4];
    if ((tid & 63) == 0) redi[tid >> 6] = cnt;
    __syncthreads();
    if (tid == 0) {
        const int c1 = redi[0] + redi[1] + redi[2] + redi[3];
        scal[0] = (float)c1 + 0.1f * (float)(NB - c1);   // m
        scal[1] = 0.f;                                   // asl accumulator
        scal[2] = 0.f;                                   // multiclass accumulator
        scal[4] = 1.f;                                   // c(0) = 1
        scal[5] = 0.f; scal[6] = 0.f; scal[7] = 0.f; scal[8] = 0.f;
        ((unsigned int*)scal)[10] = 0u;                  // finisher counter
    }
}

// ---------------- legacy init (fallback path) ----------------
__global__ __launch_bounds__(1024) void k_init(const int* __restrict__ idx,
                                               float* __restrict__ colsum,
                                               float* __restrict__ rv,
                                               float* __restrict__ scal) {
    __shared__ int red[1024];
    const int tid = threadIdx.x;
    int cnt = 0;
    for (int q = tid; q < NB; q += 1024) {
        colsum[q] = 0.f;
        rv[q] = 1.f;
        cnt += (idx[q] == 1) ? 1 : 0;
    }
    red[tid] = cnt; __syncthreads();
    for (int s = 512; s > 0; s >>= 1) {
        if (tid < s) red[tid] += red[tid + s];
        __syncthreads();
    }
    if (tid == 0) {
        const int c1 = red[0];
        scal[0] = (float)c1 + 0.1f * (float)(NB - c1);
        scal[1] = 0.f;
        scal[2] = 0.f;
    }
}

// ---------------- legacy cvt (fallback path) ----------------
__global__ __launch_bounds__(256) void k_cvt(const float4* __restrict__ src,
                                             unsigned short* __restrict__ dst, int n4) {
    const int i = blockIdx.x * 256 + threadIdx.x;
    if (i >= n4) return;
    const float4 v = src[i];
    union { unsigned short h[4]; uint2 u; } p;
    p.h[0] = f2bf(v.x); p.h[1] = f2bf(v.y); p.h[2] = f2bf(v.z); p.h[3] = f2bf(v.w);
    ((uint2*)dst)[i] = p.u;
}

// ---------------- GEMM: sim = (F @ T^T) * (1/0.07), bf16 MFMA ----------------
// 128x128 tile, BK=64, 4 waves (2x2), 16x16x32 MFMA, XOR-swizzled LDS,
// global_load_lds width 16 with pre-swizzled global source.
// fused=1: write masked coco/cifar directly (no sim buffer, no mask pass).
__global__ __launch_bounds__(256) void k_gemm(const unsigned short* __restrict__ Fb,
                                              const unsigned short* __restrict__ Tb,
                                              const int* __restrict__ idx,
                                              float* __restrict__ sim,
                                              float* __restrict__ coco,
                                              float* __restrict__ cifar,
                                              int fused) {
    __shared__ unsigned short lA[128 * 64];   // 16 KB, [row][k] bf16, swizzled
    __shared__ unsigned short lB[128 * 64];   // 16 KB
    const int tid  = threadIdx.x;
    const int lane = tid & 63;
    const int wid  = tid >> 6;                // 0..3
    const int wm = wid >> 1, wn = wid & 1;    // 2x2 wave grid, 64x64 each
    const int brow = blockIdx.y * 128;
    const int bcol = blockIdx.x * 128;

    f32x4 acc[4][4] = {};

    for (int kt = 0; kt < ND / 64; ++kt) {
        if (kt) __syncthreads();
#pragma unroll
        for (int c = 0; c < 4; ++c) {
            const int ch  = c * 4 + wid;
            const int o   = ch * 1024 + lane * 16;   // linear LDS byte
            const int row = o >> 7;                  // 128 B per row
            const int kbu = (o & 127) ^ ((row & 7) << 4); // inverse-swizzled source
            const unsigned short* gA = Fb + ((size_t)(brow + row) << 9) + (kt << 5)*2 + (kbu >> 1);
            __builtin_amdgcn_global_load_lds(
                (const __attribute__((address_space(1))) unsigned int*)gA,
                (__attribute__((address_space(3))) unsigned int*)((char*)lA + ch * 1024),
                16, 0, 0);
            const unsigned short* gB = Tb + ((size_t)(bcol + row) << 9) + (kt << 5)*2 + (kbu >> 1);
            __builtin_amdgcn_global_load_lds(
                (const __attribute__((address_space(1))) unsigned int*)gB,
                (__attribute__((address_space(3))) unsigned int*)((char*)lB + ch * 1024),
                16, 0, 0);
        }
        __syncthreads();
#pragma unroll
        for (int ks = 0; ks < 2; ++ks) {
            u32x4 af[4], bfr[4];
#pragma unroll
            for (int mi = 0; mi < 4; ++mi) {
                const int row  = wm * 64 + mi * 16 + (lane & 15);
                const int kb   = ks * 64 + ((lane >> 4) << 4);
                const int addr = row * 128 + (kb ^ ((row & 7) << 4));
                af[mi] = *(const u32x4*)((const char*)lA + addr);
            }
#pragma unroll
            for (int ni = 0; ni < 4; ++ni) {
                const int row  = wn * 64 + ni * 16 + (lane & 15);
                const int kb   = ks * 64 + ((lane >> 4) << 4);
                const int addr = row * 128 + (kb ^ ((row & 7) << 4));
                bfr[ni] = *(const u32x4*)((const char*)lB + addr);
            }
#pragma unroll
            for (int mi = 0; mi < 4; ++mi)
#pragma unroll
                for (int ni = 0; ni < 4; ++ni)
                    asm("v_mfma_f32_16x16x32_bf16 %0, %1, %2, %0"
                        : "+v"(acc[mi][ni]) : "v"(af[mi]), "v"(bfr[ni]));
        }
    }
    asm volatile("s_nop 7\n\ts_nop 7\n\ts_nop 7" ::);   // MFMA->VALU hazard fence
    if (fused) {
#pragma unroll
        for (int mi = 0; mi < 4; ++mi) {
            const int rb = brow + wm * 64 + mi * 16 + ((lane >> 4) << 2);
            int fl[4];
#pragma unroll
            for (int rr = 0; rr < 4; ++rr) fl[rr] = (idx[rb + rr] == 1);
#pragma unroll
            for (int ni = 0; ni < 4; ++ni) {
                const int col = bcol + wn * 64 + ni * 16 + (lane & 15);
#pragma unroll
                for (int rr = 0; rr < 4; ++rr) {
                    const float s = acc[mi][ni][rr] * INV_TEMP;
                    const size_t o = (size_t)(rb + rr) * NC + col;
                    coco[o]  = fl[rr] ? 0.0f : s;
                    cifar[o] = fl[rr] ? s : 0.0f;
                }
            }
        }
    } else {
#pragma unroll
        for (int mi = 0; mi < 4; ++mi) {
            const int rb = brow + wm * 64 + mi * 16 + ((lane >> 4) << 2);
#pragma unroll
            for (int ni = 0; ni < 4; ++ni) {
                const int col = bcol + wn * 64 + ni * 16 + (lane & 15);
#pragma unroll
                for (int rr = 0; rr < 4; ++rr)
                    sim[(size_t)(rb + rr) * NC + col] = acc[mi][ni][rr] * INV_TEMP;
            }
        }
    }
}

// ---------------- per-row stats + ASL loss (one block per row) ----------------
__global__ __launch_bounds__(256) void k_stats(const float* __restrict__ pc,
                                               const float* __restrict__ pf,
                                               const int* __restrict__ idx,
                                               const float* __restrict__ tgt,
                                               unsigned short* __restrict__ Ebf,
                                               float* __restrict__ rowsum0,
                                               float* __restrict__ simdiag,
                                               float* __restrict__ Arow,
                                               float* __restrict__ Tsumv,
                                               float* __restrict__ rowmx,
                                               float* __restrict__ rowmn,
                                               float* __restrict__ scal) {
    const int i = blockIdx.x, tid = threadIdx.x;
    const float* srow = ((idx[i] == 1) ? pf : pc) + (size_t)i * NC;
    const float* trow = tgt + (size_t)i * NC;
    unsigned short* erow = Ebf ? (Ebf + (size_t)i * NC) : nullptr;
    float rs = 0.f, a = 0.f, ts = 0.f, ls = 0.f;
    float mx = -3.4e38f, mn = 3.4e38f;
    for (int c = tid * 4; c < NC; c += 1024) {
        const float s0 = srow[c], s1 = srow[c+1], s2 = srow[c+2], s3 = srow[c+3];
        const float4 t4 = *(const float4*)(trow + c);
        const float t0 = t4.x, t1 = t4.y, t2 = t4.z, t3 = t4.w;
        if ((unsigned)(i - c) < 4u)
            simdiag[i] = (i == c) ? s0 : ((i == c+1) ? s1 : ((i == c+2) ? s2 : s3));
        float e0, e1, e2, e3;
#define ASL(sv, tv, ev) { \
        ev = __expf(sv); \
        rs += ev; a += (tv) * ev; ts += (tv); \
        mx = fmaxf(mx, (sv)); mn = fminf(mn, (sv)); \
        const float inv = __builtin_amdgcn_rcpf(1.0f + ev); \
        const float xsp = ev * inv; \
        const float xsn = fminf(1.05f - xsp, 1.0f); \
        const float lp  = __logf(xsp); \
        const float ln  = __logf(xsn); \
        const float pt  = xsn + (tv) * (xsp - xsn); \
        const float g   = 4.0f - 3.0f * (tv); \
        const float pw  = __builtin_amdgcn_exp2f(g * __builtin_amdgcn_logf(1.0f - pt)); \
        ls += (ln + (tv) * (lp - ln)) * pw; }
        ASL(s0, t0, e0) ASL(s1, t1, e1) ASL(s2, t2, e2) ASL(s3, t3, e3)
#undef ASL
        if (erow) {
            uint2 w;
            w.x = (unsigned)f2bf(e0) | ((unsigned)f2bf(e1) << 16);
            w.y = (unsigned)f2bf(e2) | ((unsigned)f2bf(e3) << 16);
            *(uint2*)(erow + c) = w;
        }
    }
#pragma unroll
    for (int off = 1; off < 64; off <<= 1) {
        rs += __shfl_xor(rs, off);
        a  += __shfl_xor(a , off);
        ts += __shfl_xor(ts, off);
        ls += __shfl_xor(ls, off);
        mx = fmaxf(mx, __shfl_xor(mx, off));
        mn = fminf(mn, __shfl_xor(mn, off));
    }
    __shared__ float red[4][6];
    if ((tid & 63) == 0) {
        const int w = tid >> 6;
        red[w][0] = rs; red[w][1] = a; red[w][2] = ts;
        red[w][3] = ls; red[w][4] = mx; red[w][5] = mn;
    }
    __syncthreads();
    if (tid == 0) {
        rowsum0[i] = red[0][0] + red[1][0] + red[2][0] + red[3][0];
        Arow[i]    = red[0][1] + red[1][1] + red[2][1] + red[3][1];
        Tsumv[i]   = red[0][2] + red[1][2] + red[2][2] + red[3][2];
        atomicAdd(&scal[1], red[0][3] + red[1][3] + red[2][3] + red[3][3]);
        rowmx[i] = fmaxf(fmaxf(red[0][4], red[1][4]), fmaxf(red[2][4], red[3][4]));
        rowmn[i] = fminf(fminf(red[0][5], red[1][5]), fminf(red[2][5], red[3][5]));
    }
}

// ---------------- Sinkhorn iteration t: folded update + colsum, NO global sync ----------------
// Scale-chain form: true r(t) = c(t) * u(t). Each dispatch D_t:
//   phase a (it>=1): d(t-1)_i = min(simdiag_i / (c(t-1)*csin_i), 1) computed LOCALLY for
//     this block's 64 rows from dispatch-boundary-published csin + c(t-1);
//     u(t) = u(t-1)*d; bx==0 blocks publish u(t); block(0,0) computes
//     W(t-1) = sum_i u(t)_i*rowsum0_i and publishes c(t) = m/W(t-1).
//   phase b: colsum_u(t) atomics with u(t) weights (R0-identical pattern, 64 atomics/addr).
__global__ __launch_bounds__(256) void k_csum(const unsigned short* __restrict__ Ebf,
                                              const float* __restrict__ uin,
                                              float* __restrict__ uout,
                                              const float* __restrict__ csin,
                                              float* __restrict__ csout,
                                              const float* __restrict__ simdiag,
                                              const float* __restrict__ rowsum0,
                                              float* __restrict__ scal,
                                              int it) {
    const int tid = threadIdx.x;
    const int bx = blockIdx.x;               // 0..3
    const int by = blockIdx.y;               // 0..63
    const int j  = (bx * 256 + tid) * 4;
    const int i0 = by * 64;
    __shared__ float w[64];
    __shared__ float red[4];
    float cprev = 1.f;
    if (it == 0) {
        if (tid < 64) w[tid] = 1.0f;
    } else {
        cprev = scal[4 + (it - 1)];
        if (tid < 64) {
            const int i = i0 + tid;
            const float d = fminf(simdiag[i] / (cprev * csin[i]), 1.0f);
            const float un = uin[i] * d;
            w[tid] = un;
            if (bx == 0) uout[i] = un;
        }
    }
    __syncthreads();
    float a0 = 0.f, a1 = 0.f, a2 = 0.f, a3 = 0.f;
    for (int r = 0; r < 64; ++r) {
        const uint2 u2 = *(const uint2*)(Ebf + (size_t)(i0 + r) * NC + j);
        const float rw = w[r];
        a0 += bflo(u2.x) * rw;
        a1 += bfhi(u2.x) * rw;
        a2 += bflo(u2.y) * rw;
        a3 += bfhi(u2.y) * rw;
    }
    atomicAdd(&csout[j    ], a0);
    atomicAdd(&csout[j + 1], a1);
    atomicAdd(&csout[j + 2], a2);
    atomicAdd(&csout[j + 3], a3);
    // block(0,0): publish c(t) = m / W(t-1) for the NEXT dispatch
    if (it >= 1 && bx == 0 && by == 0) {
        float acc = 0.f;
        for (int i = tid; i < NB; i += 256) {
            const float d = fminf(simdiag[i] / (cprev * csin[i]), 1.0f);
            acc += uin[i] * d * rowsum0[i];
        }
#pragma unroll
        for (int off = 1; off < 64; off <<= 1) acc += __shfl_xor(acc, off);
        if ((tid & 63) == 0) red[tid >> 6] = acc;
        __syncthreads();
        if (tid == 0) scal[4 + it] = scal[0] / (red[0] + red[1] + red[2] + red[3]);
    }
}

// ---------------- logsumexp(P row) + multiclass + final scalars (finisher) ----------------
// Final Sinkhorn update done redundantly per block: c(5) = m/W(4), r_i = c(5)*u(4)_i*d(4)_i.
__global__ __launch_bounds__(256) void k_rowfinal_e3(const unsigned short* __restrict__ Ebf,
                                                     const float* __restrict__ uin,   // u(4)
                                                     const float* __restrict__ csin,  // colsum[4]
                                                     const float* __restrict__ rowsum0,
                                                     const float* __restrict__ simdiag,
                                                     const float* __restrict__ Arow,
                                                     const float* __restrict__ Tsumv,
                                                     const float* __restrict__ rowmx,
                                                     const float* __restrict__ rowmn,
                                                     float* __restrict__ scal,
                                                     float* __restrict__ out) {
    const int i = blockIdx.x, tid = threadIdx.x;
    const float c4 = scal[8];
    __shared__ float red[4];
    // redundant W(4) reduction (hot 80 KB, L2-broadcast)
    float acc = 0.f;
    for (int q = tid; q < NB; q += 256) {
        const float d = fminf(simdiag[q] / (c4 * csin[q]), 1.0f);
        acc += uin[q] * d * rowsum0[q];
    }
#pragma unroll
    for (int off = 1; off < 64; off <<= 1) acc += __shfl_xor(acc, off);
    if ((tid & 63) == 0) red[tid >> 6] = acc;
    __syncthreads();
    const float c5 = scal[0] / (red[0] + red[1] + red[2] + red[3]);
    const float di = fminf(simdiag[i] / (c4 * csin[i]), 1.0f);
    const float ri = c5 * uin[i] * di;
    __syncthreads();                         // red[] reuse fence
    const unsigned short* erow = Ebf + (size_t)i * NC;
    const float M = ri * __expf((ri >= 0.f) ? rowmx[i] : rowmn[i]);
    float se = 0.f;
    for (int c = tid * 8; c < NC; c += 2048) {
        const uint4 u = *(const uint4*)(erow + c);
        se += __expf(ri * bflo(u.x) - M);
        se += __expf(ri * bfhi(u.x) - M);
        se += __expf(ri * bflo(u.y) - M);
        se += __expf(ri * bfhi(u.y) - M);
        se += __expf(ri * bflo(u.z) - M);
        se += __expf(ri * bfhi(u.z) - M);
        se += __expf(ri * bflo(u.w) - M);
        se += __expf(ri * bfhi(u.w) - M);
    }
#pragma unroll
    for (int off = 1; off < 64; off <<= 1) se += __shfl_xor(se, off);
    if ((tid & 63) == 0) red[tid >> 6] = se;
    __syncthreads();
    if (tid == 0) {
        const float L = M + __logf(red[0] + red[1] + red[2] + red[3]);
        atomicAdd(&scal[2], Tsumv[i] * L - ri * Arow[i]);
        __threadfence();
        if (atomicAdd(((unsigned int*)scal) + 10, 1u) == (unsigned int)(NB - 1)) {
            const float mc = atomicAdd(&scal[2], 0.0f) / (float)NB;
            const float ml = -atomicAdd(&scal[1], 0.0f);
            out[0] = mc + ml;
            out[1] = mc;
            out[2] = ml;
        }
    }
}

// ---------------- fallback kernels (no E buffer path) ----------------
__global__ __launch_bounds__(256) void k_colsum(const float* __restrict__ pc,
                                                const float* __restrict__ pf,
                                                const int* __restrict__ idx,
                                                const float* __restrict__ rv,
                                                float* __restrict__ colsum) {
    const int j  = (blockIdx.x * 256 + threadIdx.x) * 4;
    const int i0 = blockIdx.y * 32;
    float a0 = 0.f, a1 = 0.f, a2 = 0.f, a3 = 0.f;
    for (int i = i0; i < i0 + 32; ++i) {
        const float* row = ((idx[i] == 1) ? pf : pc) + (size_t)i * NC;
        const float r = rv[i];
        a0 += __expf(row[j    ]) * r;
        a1 += __expf(row[j + 1]) * r;
        a2 += __expf(row[j + 2]) * r;
        a3 += __expf(row[j + 3]) * r;
    }
    atomicAdd(&colsum[j    ], a0);
    atomicAdd(&colsum[j + 1], a1);
    atomicAdd(&colsum[j + 2], a2);
    atomicAdd(&colsum[j + 3], a3);
}

__global__ __launch_bounds__(1024) void k_update(const float* __restrict__ simdiag,
                                                 float* __restrict__ colsum,
                                                 const float* __restrict__ rowsum0,
                                                 float* __restrict__ rv,
                                                 const float* __restrict__ scal) {
    __shared__ float red[1024];
    const int tid = threadIdx.x;
    float part = 0.f;
    float rl[4];
#pragma unroll
    for (int q = 0; q < 4; ++q) {
        const int i = tid + q * 1024;
        const float d  = fminf(simdiag[i] / colsum[i], 1.0f);
        const float rn = rv[i] * d;
        rl[q] = rn;
        part += rn * rowsum0[i];
        colsum[i] = 0.f;
    }
    red[tid] = part; __syncthreads();
    for (int s = 512; s > 0; s >>= 1) {
        if (tid < s) red[tid] += red[tid + s];
        __syncthreads();
    }
    const float sc = scal[0] / red[0];
#pragma unroll
    for (int q = 0; q < 4; ++q) rv[tid + q * 1024] = rl[q] * sc;
}

__global__ __launch_bounds__(256) void k_rowfinal(const float* __restrict__ pc,
                                                  const float* __restrict__ pf,
                                                  const int* __restrict__ idx,
                                                  const float* __restrict__ rv,
                                                  const float* __restrict__ Arow,
                                                  const float* __restrict__ Tsumv,
                                                  const float* __restrict__ rowmx,
                                                  const float* __restrict__ rowmn,
                                                  float* __restrict__ scal) {
    const int i = blockIdx.x, tid = threadIdx.x;
    const float ri = rv[i];
    const float* srow = ((idx[i] == 1) ? pf : pc) + (size_t)i * NC;
    const float M = ri * __expf((ri >= 0.f) ? rowmx[i] : rowmn[i]);
    float se = 0.f;
    for (int c = tid * 4; c < NC; c += 1024) {
        se += __expf(ri * __expf(srow[c    ]) - M);
        se += __expf(ri * __expf(srow[c + 1]) - M);
        se += __expf(ri * __expf(srow[c + 2]) - M);
        se += __expf(ri * __expf(srow[c + 3]) - M);
    }
#pragma unroll
    for (int off = 1; off < 64; off <<= 1) se += __shfl_xor(se, off);
    __shared__ float red[4];
    if ((tid & 63) == 0) red[tid >> 6] = se;
    __syncthreads();
    if (tid == 0) {
        const float L = M + __logf(red[0] + red[1] + red[2] + red[3]);
        atomicAdd(&scal[2], Tsumv[i] * L - ri * Arow[i]);
    }
}

__global__ void k_scalars(const float* __restrict__ scal, float* __restrict__ out) {
    if (threadIdx.x == 0) {
        const float mc = scal[2] / (float)NB;
        const float ml = -scal[1];
        out[0] = mc + ml;
        out[1] = mc;
        out[2] = ml;
    }
}

__global__ __launch_bounds__(256) void k_mask(const float* sim, const int* idx,
                                              float* coco, float* cifar) {
    const int i = blockIdx.y;
    const int c = blockIdx.x * 256 + threadIdx.x;
    const size_t o = (size_t)i * NC + c;
    const float s = sim[o];
    const bool isCifar = (idx[i] == 1);
    coco[o]  = isCifar ? 0.0f : s;
    cifar[o] = isCifar ? s : 0.0f;
}

extern "C" void kernel_launch(void* const* d_in, const int* in_sizes, int n_in,
                              void* d_out, int out_size, void* d_ws, size_t ws_size,
                              hipStream_t stream) {
    const float* F   = (const float*)d_in[0];   // [4096,512]
    const float* T   = (const float*)d_in[1];   // [8192,512]
    const float* tgt = (const float*)d_in[2];   // [4096,8192]
    const int*   idx = (const int*)d_in[3];     // [4096]

    float* out   = (float*)d_out;
    float* coco  = out + 3;
    float* cifar = coco + (size_t)NB * NC;

    const size_t FbBytes    = (size_t)NB * ND * 2;      // 4 MB
    const size_t TbBytes    = (size_t)NC * ND * 2;      // 8 MB
    const size_t EBytes     = (size_t)NB * NC * 2;      // 67 MB
    const size_t smallBytes = 14 * (size_t)NB * 4 + 1024;

    const bool fused = (d_ws != nullptr) &&
                       (ws_size >= FbBytes + TbBytes + smallBytes + 512);
    const bool hasE  = (d_ws != nullptr) &&
                       (ws_size >= FbBytes + TbBytes + EBytes + smallBytes + 512);
    unsigned short *Fb, *Tb, *Ebf = nullptr;
    float *sm, *sim;
    if (fused) {
        Fb  = (unsigned short*)d_ws;
        Tb  = (unsigned short*)((char*)d_ws + FbBytes);
        char* p = (char*)d_ws + FbBytes + TbBytes;
        if (hasE) { Ebf = (unsigned short*)p; p += EBytes; }
        sm  = (float*)p;
        sim = nullptr;
    } else {
        sim = cifar;
        char* base = (char*)(((uintptr_t)(void*)coco + 255) & ~(uintptr_t)255);
        Fb  = (unsigned short*)base;
        Tb  = (unsigned short*)(base + FbBytes);
        sm  = (float*)(base + FbBytes + TbBytes);
    }
    float* csum    = sm;              // 5 slots of NB (fallback uses slot 0)
    float* uA      = sm + 5 * NB;     // fallback: rv
    float* uB      = sm + 6 * NB;
    float* rowsum0 = sm + 7 * NB;
    float* simdiag = sm + 8 * NB;
    float* Arow    = sm + 9 * NB;
    float* Tsumv   = sm + 10 * NB;
    float* rowmx   = sm + 11 * NB;
    float* rowmn   = sm + 12 * NB;
    float* scal    = sm + 13 * NB;

    if (hasE) {
        // ---- 9-dispatch path ----
        k_prep<<<6145, 256, 0, stream>>>((const float4*)F, (const float4*)T, Fb, Tb,
                                         idx, csum, uA, scal);
        k_gemm<<<dim3(NC / 128, NB / 128), 256, 0, stream>>>(Fb, Tb, idx, nullptr,
                                                             coco, cifar, 1);
        k_stats<<<NB, 256, 0, stream>>>(coco, cifar, idx, tgt, Ebf, rowsum0, simdiag,
                                        Arow, Tsumv, rowmx, rowmn, scal);
        // u ping-pong: u(0)=uA, u(1)=uB, u(2)=uA, u(3)=uB, u(4)=uA
        for (int it = 0; it < 5; ++it) {
            float* uin  = (it & 1) ? uB : uA;   // u(t-1): it=1 reads uA, it=2 reads uB...
            float* uout = (it & 1) ? uA : uB;
            if (it == 0) { uin = uA; uout = uB; }        // unused weights path
            else if (!(it & 1)) { uin = uB; uout = uA; } // even it>=2
            else { uin = uA; uout = uB; }                // odd it
            // explicit: it=1: uA->uB, it=2: uB->uA, it=3: uA->uB, it=4: uB->uA
            if (it == 1 || it == 3) { uin = uA; uout = uB; }
            if (it == 2 || it == 4) { uin = uB; uout = uA; }
            k_csum<<<dim3(4, 64), 256, 0, stream>>>(Ebf, uin, uout,
                                                    csum + (it ? (it - 1) : 0) * NB,
                                                    csum + it * NB,
                                                    simdiag, rowsum0, scal, it);
        }
        k_rowfinal_e3<<<NB, 256, 0, stream>>>(Ebf, uA /*u(4)*/, csum + 4 * NB, rowsum0,
                                              simdiag, Arow, Tsumv, rowmx, rowmn,
                                              scal, out);
        return;
    }

    // ---- fallback path (no E buffer) ----
    float* colsum = csum;
    float* rv     = uA;
    const float* pc = fused ? coco  : sim;
    const float* pf = fused ? cifar : sim;

    k_init<<<1, 1024, 0, stream>>>(idx, colsum, rv, scal);
    k_cvt<<<(NB * ND / 4) / 256, 256, 0, stream>>>((const float4*)F, Fb, NB * ND / 4);
    k_cvt<<<(NC * ND / 4) / 256, 256, 0, stream>>>((const float4*)T, Tb, NC * ND / 4);
    k_gemm<<<dim3(NC / 128, NB / 128), 256, 0, stream>>>(Fb, Tb, idx, sim, coco, cifar,
                                                         fused ? 1 : 0);
    k_stats<<<NB, 256, 0, stream>>>(pc, pf, idx, tgt, nullptr, rowsum0, simdiag, Arow, Tsumv,
                                    rowmx, rowmn, scal);
    for (int it = 0; it < 5; ++it) {
        k_colsum<<<dim3(NB / 1024, 128), 256, 0, stream>>>(pc, pf, idx, rv, colsum);
        k_update<<<1, 1024, 0, stream>>>(simdiag, colsum, rowsum0, rv, scal);
    }
    k_rowfinal<<<NB, 256, 0, stream>>>(pc, pf, idx, rv, Arow, Tsumv, rowmx, rowmn, scal);
    k_scalars<<<1, 64, 0, stream>>>(scal, out);
    if (!fused) k_mask<<<dim3(NC / 256, NB), 256, 0, stream>>>(sim, idx, coco, cifar);
}

// Round 6
// 393.837 us; speedup vs baseline: 3.8810x; 1.0228x over previous
//
#include <hip/hip_runtime.h>
#include <stdint.h>

#define NB 4096            // batch rows
#define NC 8192            // classes / text rows
#define ND 512             // feature dim
#define INV_TEMP (1.0f/0.07f)

typedef float  f32x4 __attribute__((ext_vector_type(4)));
typedef unsigned int u32x4 __attribute__((ext_vector_type(4)));

__device__ __forceinline__ unsigned short f2bf(float f) {
    unsigned int u = __float_as_uint(f);
    u += 0x7fffu + ((u >> 16) & 1u);          // RNE
    return (unsigned short)(u >> 16);
}
__device__ __forceinline__ float bflo(unsigned int u) {   // low 16 bits -> f32
    return __uint_as_float(u << 16);
}
__device__ __forceinline__ float bfhi(unsigned int u) {   // high 16 bits -> f32
    return __uint_as_float(u & 0xFFFF0000u);
}

// ---------------- prep: F/T -> bf16 convert + init state, ONE dispatch ----------------
// blocks [0, 6144): cvt (F first 2048, T next 4096); block 6144: init.
// scal: [0]=m  [1]=asl acc  [2]=mc acc  u32[10]=rowfinal finisher counter
__global__ __launch_bounds__(256) void k_prep(const float4* __restrict__ F4,
                                              const float4* __restrict__ T4,
                                              unsigned short* __restrict__ Fb,
                                              unsigned short* __restrict__ Tb,
                                              const int* __restrict__ idx,
                                              float* __restrict__ colsum,
                                              float* __restrict__ rv,
                                              float* __restrict__ scal) {
    const int tid = threadIdx.x;
    const int b = blockIdx.x;
    if (b < 6144) {
        const int i  = b * 256 + tid;
        const int nF = NB * ND / 4;
        const float4 v = (i < nF) ? F4[i] : T4[i - nF];
        union { unsigned short h[4]; uint2 u; } p;
        p.h[0] = f2bf(v.x); p.h[1] = f2bf(v.y); p.h[2] = f2bf(v.z); p.h[3] = f2bf(v.w);
        if (i < nF) ((uint2*)Fb)[i] = p.u;
        else        ((uint2*)Tb)[i - nF] = p.u;
        return;
    }
    // init block
    int cnt = 0;
    for (int q = tid; q < NB; q += 256) {
        colsum[q] = 0.f;
        rv[q] = 1.f;
        cnt += (idx[q] == 1) ? 1 : 0;
    }
#pragma unroll
    for (int off = 1; off < 64; off <<= 1) cnt += __shfl_xor(cnt, off);
    __shared__ int redi[4];
    if ((tid & 63) == 0) redi[tid >> 6] = cnt;
    __syncthreads();
    if (tid == 0) {
        const int c1 = redi[0] + redi[1] + redi[2] + redi[3];
        scal[0] = (float)c1 + 0.1f * (float)(NB - c1);   // m
        scal[1] = 0.f;                                   // asl accumulator
        scal[2] = 0.f;                                   // multiclass accumulator
        ((unsigned int*)scal)[10] = 0u;                  // finisher counter
    }
}

// ---------------- legacy init (fallback path) ----------------
__global__ __launch_bounds__(1024) void k_init(const int* __restrict__ idx,
                                               float* __restrict__ colsum,
                                               float* __restrict__ rv,
                                               float* __restrict__ scal) {
    __shared__ int red[1024];
    const int tid = threadIdx.x;
    int cnt = 0;
    for (int q = tid; q < NB; q += 1024) {
        colsum[q] = 0.f;
        rv[q] = 1.f;
        cnt += (idx[q] == 1) ? 1 : 0;
    }
    red[tid] = cnt; __syncthreads();
    for (int s = 512; s > 0; s >>= 1) {
        if (tid < s) red[tid] += red[tid + s];
        __syncthreads();
    }
    if (tid == 0) {
        const int c1 = red[0];
        scal[0] = (float)c1 + 0.1f * (float)(NB - c1);
        scal[1] = 0.f;
        scal[2] = 0.f;
    }
}

// ---------------- legacy cvt (fallback path) ----------------
__global__ __launch_bounds__(256) void k_cvt(const float4* __restrict__ src,
                                             unsigned short* __restrict__ dst, int n4) {
    const int i = blockIdx.x * 256 + threadIdx.x;
    if (i >= n4) return;
    const float4 v = src[i];
    union { unsigned short h[4]; uint2 u; } p;
    p.h[0] = f2bf(v.x); p.h[1] = f2bf(v.y); p.h[2] = f2bf(v.z); p.h[3] = f2bf(v.w);
    ((uint2*)dst)[i] = p.u;
}

// ---------------- GEMM: sim = (F @ T^T) * (1/0.07), bf16 MFMA ----------------
// 128x128 tile, BK=64, 4 waves (2x2), 16x16x32 MFMA, XOR-swizzled LDS,
// global_load_lds width 16 with pre-swizzled global source.
// fused=1: write masked coco/cifar directly (no sim buffer, no mask pass).
__global__ __launch_bounds__(256) void k_gemm(const unsigned short* __restrict__ Fb,
                                              const unsigned short* __restrict__ Tb,
                                              const int* __restrict__ idx,
                                              float* __restrict__ sim,
                                              float* __restrict__ coco,
                                              float* __restrict__ cifar,
                                              int fused) {
    __shared__ unsigned short lA[128 * 64];   // 16 KB, [row][k] bf16, swizzled
    __shared__ unsigned short lB[128 * 64];   // 16 KB
    const int tid  = threadIdx.x;
    const int lane = tid & 63;
    const int wid  = tid >> 6;                // 0..3
    const int wm = wid >> 1, wn = wid & 1;    // 2x2 wave grid, 64x64 each
    const int brow = blockIdx.y * 128;
    const int bcol = blockIdx.x * 128;

    f32x4 acc[4][4] = {};

    for (int kt = 0; kt < ND / 64; ++kt) {
        if (kt) __syncthreads();
#pragma unroll
        for (int c = 0; c < 4; ++c) {
            const int ch  = c * 4 + wid;
            const int o   = ch * 1024 + lane * 16;   // linear LDS byte
            const int row = o >> 7;                  // 128 B per row
            const int kbu = (o & 127) ^ ((row & 7) << 4); // inverse-swizzled source
            const unsigned short* gA = Fb + ((size_t)(brow + row) << 9) + (kt << 5)*2 + (kbu >> 1);
            __builtin_amdgcn_global_load_lds(
                (const __attribute__((address_space(1))) unsigned int*)gA,
                (__attribute__((address_space(3))) unsigned int*)((char*)lA + ch * 1024),
                16, 0, 0);
            const unsigned short* gB = Tb + ((size_t)(bcol + row) << 9) + (kt << 5)*2 + (kbu >> 1);
            __builtin_amdgcn_global_load_lds(
                (const __attribute__((address_space(1))) unsigned int*)gB,
                (__attribute__((address_space(3))) unsigned int*)((char*)lB + ch * 1024),
                16, 0, 0);
        }
        __syncthreads();
#pragma unroll
        for (int ks = 0; ks < 2; ++ks) {
            u32x4 af[4], bfr[4];
#pragma unroll
            for (int mi = 0; mi < 4; ++mi) {
                const int row  = wm * 64 + mi * 16 + (lane & 15);
                const int kb   = ks * 64 + ((lane >> 4) << 4);
                const int addr = row * 128 + (kb ^ ((row & 7) << 4));
                af[mi] = *(const u32x4*)((const char*)lA + addr);
            }
#pragma unroll
            for (int ni = 0; ni < 4; ++ni) {
                const int row  = wn * 64 + ni * 16 + (lane & 15);
                const int kb   = ks * 64 + ((lane >> 4) << 4);
                const int addr = row * 128 + (kb ^ ((row & 7) << 4));
                bfr[ni] = *(const u32x4*)((const char*)lB + addr);
            }
#pragma unroll
            for (int mi = 0; mi < 4; ++mi)
#pragma unroll
                for (int ni = 0; ni < 4; ++ni)
                    asm("v_mfma_f32_16x16x32_bf16 %0, %1, %2, %0"
                        : "+v"(acc[mi][ni]) : "v"(af[mi]), "v"(bfr[ni]));
        }
    }
    asm volatile("s_nop 7\n\ts_nop 7\n\ts_nop 7" ::);   // MFMA->VALU hazard fence
    if (fused) {
#pragma unroll
        for (int mi = 0; mi < 4; ++mi) {
            const int rb = brow + wm * 64 + mi * 16 + ((lane >> 4) << 2);
            int fl[4];
#pragma unroll
            for (int rr = 0; rr < 4; ++rr) fl[rr] = (idx[rb + rr] == 1);
#pragma unroll
            for (int ni = 0; ni < 4; ++ni) {
                const int col = bcol + wn * 64 + ni * 16 + (lane & 15);
#pragma unroll
                for (int rr = 0; rr < 4; ++rr) {
                    const float s = acc[mi][ni][rr] * INV_TEMP;
                    const size_t o = (size_t)(rb + rr) * NC + col;
                    coco[o]  = fl[rr] ? 0.0f : s;
                    cifar[o] = fl[rr] ? s : 0.0f;
                }
            }
        }
    } else {
#pragma unroll
        for (int mi = 0; mi < 4; ++mi) {
            const int rb = brow + wm * 64 + mi * 16 + ((lane >> 4) << 2);
#pragma unroll
            for (int ni = 0; ni < 4; ++ni) {
                const int col = bcol + wn * 64 + ni * 16 + (lane & 15);
#pragma unroll
                for (int rr = 0; rr < 4; ++rr)
                    sim[(size_t)(rb + rr) * NC + col] = acc[mi][ni][rr] * INV_TEMP;
            }
        }
    }
}

// ---------------- per-row stats + ASL loss (one block per row) ----------------
// Fast ASL: sigmoid from shared exp, pow via exp2/log2 builtins.
// Optionally writes Ebf[i][c] = bf16(exp(sim)) for reuse by colsum/rowfinal.
__global__ __launch_bounds__(256) void k_stats(const float* __restrict__ pc,
                                               const float* __restrict__ pf,
                                               const int* __restrict__ idx,
                                               const float* __restrict__ tgt,
                                               unsigned short* __restrict__ Ebf,
                                               float* __restrict__ rowsum0,
                                               float* __restrict__ simdiag,
                                               float* __restrict__ Arow,
                                               float* __restrict__ Tsumv,
                                               float* __restrict__ rowmx,
                                               float* __restrict__ rowmn,
                                               float* __restrict__ scal) {
    const int i = blockIdx.x, tid = threadIdx.x;
    const float* srow = ((idx[i] == 1) ? pf : pc) + (size_t)i * NC;
    const float* trow = tgt + (size_t)i * NC;
    unsigned short* erow = Ebf ? (Ebf + (size_t)i * NC) : nullptr;
    float rs = 0.f, a = 0.f, ts = 0.f, ls = 0.f;
    float mx = -3.4e38f, mn = 3.4e38f;
    for (int c = tid * 4; c < NC; c += 1024) {
        const float s0 = srow[c], s1 = srow[c+1], s2 = srow[c+2], s3 = srow[c+3];
        const float4 t4 = *(const float4*)(trow + c);
        const float t0 = t4.x, t1 = t4.y, t2 = t4.z, t3 = t4.w;
        if ((unsigned)(i - c) < 4u)
            simdiag[i] = (i == c) ? s0 : ((i == c+1) ? s1 : ((i == c+2) ? s2 : s3));
        float e0, e1, e2, e3;
#define ASL(sv, tv, ev) { \
        ev = __expf(sv); \
        rs += ev; a += (tv) * ev; ts += (tv); \
        mx = fmaxf(mx, (sv)); mn = fminf(mn, (sv)); \
        const float inv = __builtin_amdgcn_rcpf(1.0f + ev); \
        const float xsp = ev * inv; \
        const float xsn = fminf(1.05f - xsp, 1.0f); \
        const float lp  = __logf(xsp); \
        const float ln  = __logf(xsn); \
        const float pt  = xsn + (tv) * (xsp - xsn); \
        const float g   = 4.0f - 3.0f * (tv); \
        const float pw  = __builtin_amdgcn_exp2f(g * __builtin_amdgcn_logf(1.0f - pt)); \
        ls += (ln + (tv) * (lp - ln)) * pw; }
        ASL(s0, t0, e0) ASL(s1, t1, e1) ASL(s2, t2, e2) ASL(s3, t3, e3)
#undef ASL
        if (erow) {
            uint2 w;
            w.x = (unsigned)f2bf(e0) | ((unsigned)f2bf(e1) << 16);
            w.y = (unsigned)f2bf(e2) | ((unsigned)f2bf(e3) << 16);
            *(uint2*)(erow + c) = w;
        }
    }
#pragma unroll
    for (int off = 1; off < 64; off <<= 1) {
        rs += __shfl_xor(rs, off);
        a  += __shfl_xor(a , off);
        ts += __shfl_xor(ts, off);
        ls += __shfl_xor(ls, off);
        mx = fmaxf(mx, __shfl_xor(mx, off));
        mn = fminf(mn, __shfl_xor(mn, off));
    }
    __shared__ float red[4][6];
    if ((tid & 63) == 0) {
        const int w = tid >> 6;
        red[w][0] = rs; red[w][1] = a; red[w][2] = ts;
        red[w][3] = ls; red[w][4] = mx; red[w][5] = mn;
    }
    __syncthreads();
    if (tid == 0) {
        rowsum0[i] = red[0][0] + red[1][0] + red[2][0] + red[3][0];
        Arow[i]    = red[0][1] + red[1][1] + red[2][1] + red[3][1];
        Tsumv[i]   = red[0][2] + red[1][2] + red[2][2] + red[3][2];
        atomicAdd(&scal[1], red[0][3] + red[1][3] + red[2][3] + red[3][3]);
        rowmx[i] = fmaxf(fmaxf(red[0][4], red[1][4]), fmaxf(red[2][4], red[3][4]));
        rowmn[i] = fminf(fminf(red[0][5], red[1][5]), fminf(red[2][5], red[3][5]));
    }
}

// ---------------- colsum from cached bf16 E:  colsum[j] = sum_i E[i][j]*r[i] ----------------
__global__ __launch_bounds__(256) void k_colsum_e(const unsigned short* __restrict__ Ebf,
                                                  const float* __restrict__ rv,
                                                  float* __restrict__ colsum) {
    const int j  = (blockIdx.x * 256 + threadIdx.x) * 4;   // gridx = NB/1024 = 4
    const int i0 = blockIdx.y * 64;                        // gridy = 64
    float a0 = 0.f, a1 = 0.f, a2 = 0.f, a3 = 0.f;
    for (int i = i0; i < i0 + 64; ++i) {
        const uint2 u = *(const uint2*)(Ebf + (size_t)i * NC + j);
        const float r = rv[i];
        a0 += bflo(u.x) * r;
        a1 += bfhi(u.x) * r;
        a2 += bflo(u.y) * r;
        a3 += bfhi(u.y) * r;
    }
    atomicAdd(&colsum[j    ], a0);
    atomicAdd(&colsum[j + 1], a1);
    atomicAdd(&colsum[j + 2], a2);
    atomicAdd(&colsum[j + 3], a3);
}

// ---------------- fallback colsum (no E buffer) ----------------
__global__ __launch_bounds__(256) void k_colsum(const float* __restrict__ pc,
                                                const float* __restrict__ pf,
                                                const int* __restrict__ idx,
                                                const float* __restrict__ rv,
                                                float* __restrict__ colsum) {
    const int j  = (blockIdx.x * 256 + threadIdx.x) * 4;   // gridx = NB/1024 = 4
    const int i0 = blockIdx.y * 32;                        // gridy = 128
    float a0 = 0.f, a1 = 0.f, a2 = 0.f, a3 = 0.f;
    for (int i = i0; i < i0 + 32; ++i) {
        const float* row = ((idx[i] == 1) ? pf : pc) + (size_t)i * NC;
        const float r = rv[i];
        a0 += __expf(row[j    ]) * r;
        a1 += __expf(row[j + 1]) * r;
        a2 += __expf(row[j + 2]) * r;
        a3 += __expf(row[j + 3]) * r;
    }
    atomicAdd(&colsum[j    ], a0);
    atomicAdd(&colsum[j + 1], a1);
    atomicAdd(&colsum[j + 2], a2);
    atomicAdd(&colsum[j + 3], a3);
}

// ---------------- per-iteration scalar update of r ----------------
__global__ __launch_bounds__(1024) void k_update(const float* __restrict__ simdiag,
                                                 float* __restrict__ colsum,
                                                 const float* __restrict__ rowsum0,
                                                 float* __restrict__ rv,
                                                 const float* __restrict__ scal) {
    __shared__ float red[1024];
    const int tid = threadIdx.x;
    float part = 0.f;
    float rl[4];
#pragma unroll
    for (int q = 0; q < 4; ++q) {
        const int i = tid + q * 1024;
        const float d  = fminf(simdiag[i] / colsum[i], 1.0f);
        const float rn = rv[i] * d;
        rl[q] = rn;
        part += rn * rowsum0[i];
        colsum[i] = 0.f;                    // reset for next iteration
    }
    red[tid] = part; __syncthreads();
    for (int s = 512; s > 0; s >>= 1) {
        if (tid < s) red[tid] += red[tid + s];
        __syncthreads();
    }
    const float sc = scal[0] / red[0];      // m / P.sum()
#pragma unroll
    for (int q = 0; q < 4; ++q) rv[tid + q * 1024] = rl[q] * sc;
}

// ---------------- logsumexp(P row) + multiclass accumulation + finisher ----------------
__global__ __launch_bounds__(256) void k_rowfinal_e(const unsigned short* __restrict__ Ebf,
                                                    const float* __restrict__ rv,
                                                    const float* __restrict__ Arow,
                                                    const float* __restrict__ Tsumv,
                                                    const float* __restrict__ rowmx,
                                                    const float* __restrict__ rowmn,
                                                    float* __restrict__ scal,
                                                    float* __restrict__ out) {
    const int i = blockIdx.x, tid = threadIdx.x;
    const float ri = rv[i];
    const unsigned short* erow = Ebf + (size_t)i * NC;
    // max of P row: ri>=0 -> ri*exp(rowmax); ri<0 -> ri*exp(rowmin).
    const float M = ri * __expf((ri >= 0.f) ? rowmx[i] : rowmn[i]);
    float se = 0.f;
    for (int c = tid * 8; c < NC; c += 2048) {
        const uint4 u = *(const uint4*)(erow + c);
        se += __expf(ri * bflo(u.x) - M);
        se += __expf(ri * bfhi(u.x) - M);
        se += __expf(ri * bflo(u.y) - M);
        se += __expf(ri * bfhi(u.y) - M);
        se += __expf(ri * bflo(u.z) - M);
        se += __expf(ri * bfhi(u.z) - M);
        se += __expf(ri * bflo(u.w) - M);
        se += __expf(ri * bfhi(u.w) - M);
    }
#pragma unroll
    for (int off = 1; off < 64; off <<= 1) se += __shfl_xor(se, off);
    __shared__ float red[4];
    if ((tid & 63) == 0) red[tid >> 6] = se;
    __syncthreads();
    if (tid == 0) {
        const float L = M + __logf(red[0] + red[1] + red[2] + red[3]);
        atomicAdd(&scal[2], Tsumv[i] * L - ri * Arow[i]);
        __threadfence();
        if (atomicAdd(((unsigned int*)scal) + 10, 1u) == (unsigned int)(NB - 1)) {
            const float mc = atomicAdd(&scal[2], 0.0f) / (float)NB;
            const float ml = -atomicAdd(&scal[1], 0.0f);
            out[0] = mc + ml;
            out[1] = mc;
            out[2] = ml;
        }
    }
}

// ---------------- fallback rowfinal (no E buffer) ----------------
__global__ __launch_bounds__(256) void k_rowfinal(const float* __restrict__ pc,
                                                  const float* __restrict__ pf,
                                                  const int* __restrict__ idx,
                                                  const float* __restrict__ rv,
                                                  const float* __restrict__ Arow,
                                                  const float* __restrict__ Tsumv,
                                                  const float* __restrict__ rowmx,
                                                  const float* __restrict__ rowmn,
                                                  float* __restrict__ scal) {
    const int i = blockIdx.x, tid = threadIdx.x;
    const float ri = rv[i];
    const float* srow = ((idx[i] == 1) ? pf : pc) + (size_t)i * NC;
    const float M = ri * __expf((ri >= 0.f) ? rowmx[i] : rowmn[i]);
    float se = 0.f;
    for (int c = tid * 4; c < NC; c += 1024) {
        se += __expf(ri * __expf(srow[c    ]) - M);
        se += __expf(ri * __expf(srow[c + 1]) - M);
        se += __expf(ri * __expf(srow[c + 2]) - M);
        se += __expf(ri * __expf(srow[c + 3]) - M);
    }
#pragma unroll
    for (int off = 1; off < 64; off <<= 1) se += __shfl_xor(se, off);
    __shared__ float red[4];
    if ((tid & 63) == 0) red[tid >> 6] = se;
    __syncthreads();
    if (tid == 0) {
        const float L = M + __logf(red[0] + red[1] + red[2] + red[3]);
        atomicAdd(&scal[2], Tsumv[i] * L - ri * Arow[i]);
    }
}

// ---------------- final scalars (fallback path) ----------------
__global__ void k_scalars(const float* __restrict__ scal, float* __restrict__ out) {
    if (threadIdx.x == 0) {
        const float mc = scal[2] / (float)NB;
        const float ml = -scal[1];
        out[0] = mc + ml;
        out[1] = mc;
        out[2] = ml;
    }
}

// ---------------- masked sim outputs (fallback path; sim aliases cifar) ----------------
__global__ __launch_bounds__(256) void k_mask(const float* sim, const int* idx,
                                              float* coco, float* cifar) {
    const int i = blockIdx.y;
    const int c = blockIdx.x * 256 + threadIdx.x;
    const size_t o = (size_t)i * NC + c;
    const float s = sim[o];                 // read before any aliased write
    const bool isCifar = (idx[i] == 1);
    coco[o]  = isCifar ? 0.0f : s;
    cifar[o] = isCifar ? s : 0.0f;
}

extern "C" void kernel_launch(void* const* d_in, const int* in_sizes, int n_in,
                              void* d_out, int out_size, void* d_ws, size_t ws_size,
                              hipStream_t stream) {
    const float* F   = (const float*)d_in[0];   // [4096,512]
    const float* T   = (const float*)d_in[1];   // [8192,512]
    const float* tgt = (const float*)d_in[2];   // [4096,8192]
    const int*   idx = (const int*)d_in[3];     // [4096]

    float* out   = (float*)d_out;
    float* coco  = out + 3;
    float* cifar = coco + (size_t)NB * NC;

    const size_t FbBytes    = (size_t)NB * ND * 2;      // 4 MB
    const size_t TbBytes    = (size_t)NC * ND * 2;      // 8 MB
    const size_t EBytes     = (size_t)NB * NC * 2;      // 67 MB
    const size_t smallBytes = 10 * (size_t)NB * 4 + 1024;

    const bool fused = (d_ws != nullptr) &&
                       (ws_size >= FbBytes + TbBytes + smallBytes + 512);
    const bool hasE  = (d_ws != nullptr) &&
                       (ws_size >= FbBytes + TbBytes + EBytes + smallBytes + 512);
    unsigned short *Fb, *Tb, *Ebf = nullptr;
    float *sm, *sim;
    if (fused) {
        Fb  = (unsigned short*)d_ws;
        Tb  = (unsigned short*)((char*)d_ws + FbBytes);
        char* p = (char*)d_ws + FbBytes + TbBytes;
        if (hasE) { Ebf = (unsigned short*)p; p += EBytes; }
        sm  = (float*)p;
        sim = nullptr;
    } else {
        // sim lives in the cifar output slot; bf16 copies + small vectors in the
        // coco slot head (dead until k_mask, which runs last).
        sim = cifar;
        char* base = (char*)(((uintptr_t)(void*)coco + 255) & ~(uintptr_t)255);
        Fb  = (unsigned short*)base;
        Tb  = (unsigned short*)(base + FbBytes);
        sm  = (float*)(base + FbBytes + TbBytes);
    }
    float* colsum  = sm;
    float* rv      = sm + NB;
    float* rowsum0 = sm + 2 * NB;
    float* simdiag = sm + 3 * NB;
    float* Arow    = sm + 4 * NB;
    float* Tsumv   = sm + 5 * NB;
    float* rowmx   = sm + 6 * NB;
    float* rowmn   = sm + 7 * NB;
    float* scal    = sm + 8 * NB;

    const float* pc = fused ? coco  : sim;
    const float* pf = fused ? cifar : sim;

    if (hasE) {
        // ---- 13-dispatch path: R0 hot kernels + validated merges only ----
        k_prep<<<6145, 256, 0, stream>>>((const float4*)F, (const float4*)T, Fb, Tb,
                                         idx, colsum, rv, scal);
        k_gemm<<<dim3(NC / 128, NB / 128), 256, 0, stream>>>(Fb, Tb, idx, nullptr,
                                                             coco, cifar, 1);
        k_stats<<<NB, 256, 0, stream>>>(pc, pf, idx, tgt, Ebf, rowsum0, simdiag, Arow,
                                        Tsumv, rowmx, rowmn, scal);
        for (int it = 0; it < 5; ++it) {
            k_colsum_e<<<dim3(NB / 1024, 64), 256, 0, stream>>>(Ebf, rv, colsum);
            k_update<<<1, 1024, 0, stream>>>(simdiag, colsum, rowsum0, rv, scal);
        }
        k_rowfinal_e<<<NB, 256, 0, stream>>>(Ebf, rv, Arow, Tsumv, rowmx, rowmn,
                                             scal, out);
        return;
    }

    // ---- fallback path (no E buffer) ----
    k_init<<<1, 1024, 0, stream>>>(idx, colsum, rv, scal);
    k_cvt<<<(NB * ND / 4) / 256, 256, 0, stream>>>((const float4*)F, Fb, NB * ND / 4);
    k_cvt<<<(NC * ND / 4) / 256, 256, 0, stream>>>((const float4*)T, Tb, NC * ND / 4);
    k_gemm<<<dim3(NC / 128, NB / 128), 256, 0, stream>>>(Fb, Tb, idx, sim, coco, cifar,
                                                         fused ? 1 : 0);
    k_stats<<<NB, 256, 0, stream>>>(pc, pf, idx, tgt, nullptr, rowsum0, simdiag, Arow, Tsumv,
                                    rowmx, rowmn, scal);
    for (int it = 0; it < 5; ++it) {
        k_colsum<<<dim3(NB / 1024, 128), 256, 0, stream>>>(pc, pf, idx, rv, colsum);
        k_update<<<1, 1024, 0, stream>>>(simdiag, colsum, rowsum0, rv, scal);
    }
    k_rowfinal<<<NB, 256, 0, stream>>>(pc, pf, idx, rv, Arow, Tsumv, rowmx, rowmn, scal);
    k_scalars<<<1, 64, 0, stream>>>(scal, out);
    if (!fused) k_mask<<<dim3(NC / 256, NB), 256, 0, stream>>>(sim, idx, coco, cifar);
}

// Round 7
// 332.148 us; speedup vs baseline: 4.6019x; 1.1857x over previous
//
#include <hip/hip_runtime.h>
#include <stdint.h>

#define NB 4096            // batch rows
#define NC 8192            // classes / text rows
#define ND 512             // feature dim
#define INV_TEMP (1.0f/0.07f)

typedef float  f32x4 __attribute__((ext_vector_type(4)));
typedef unsigned int u32x4 __attribute__((ext_vector_type(4)));

__device__ __forceinline__ unsigned short f2bf(float f) {
    unsigned int u = __float_as_uint(f);
    u += 0x7fffu + ((u >> 16) & 1u);          // RNE
    return (unsigned short)(u >> 16);
}
__device__ __forceinline__ float bflo(unsigned int u) {   // low 16 bits -> f32
    return __uint_as_float(u << 16);
}
__device__ __forceinline__ float bfhi(unsigned int u) {   // high 16 bits -> f32
    return __uint_as_float(u & 0xFFFF0000u);
}

// ---------------- init: zero accumulators, compute m, r=1 ----------------
__global__ __launch_bounds__(1024) void k_init(const int* __restrict__ idx,
                                               float* __restrict__ colsum,
                                               float* __restrict__ rv,
                                               float* __restrict__ scal) {
    __shared__ int red[1024];
    const int tid = threadIdx.x;
    int cnt = 0;
    for (int q = tid; q < NB; q += 1024) {
        colsum[q] = 0.f;
        rv[q] = 1.f;
        cnt += (idx[q] == 1) ? 1 : 0;
    }
    red[tid] = cnt; __syncthreads();
    for (int s = 512; s > 0; s >>= 1) {
        if (tid < s) red[tid] += red[tid + s];
        __syncthreads();
    }
    if (tid == 0) {
        const int c1 = red[0];
        scal[0] = (float)c1 + 0.1f * (float)(NB - c1);   // m
        scal[1] = 0.f;                                   // asl accumulator
        scal[2] = 0.f;                                   // multiclass accumulator
    }
}

// ---------------- f32 -> bf16 convert (vectorized) ----------------
__global__ __launch_bounds__(256) void k_cvt(const float4* __restrict__ src,
                                             unsigned short* __restrict__ dst, int n4) {
    const int i = blockIdx.x * 256 + threadIdx.x;
    if (i >= n4) return;
    const float4 v = src[i];
    union { unsigned short h[4]; uint2 u; } p;
    p.h[0] = f2bf(v.x); p.h[1] = f2bf(v.y); p.h[2] = f2bf(v.z); p.h[3] = f2bf(v.w);
    ((uint2*)dst)[i] = p.u;
}

// ---------------- GEMM: sim = (F @ T^T) * (1/0.07), bf16 MFMA ----------------
// 128x128 tile, BK=64, 4 waves (2x2), 16x16x32 MFMA, XOR-swizzled LDS,
// global_load_lds width 16 with pre-swizzled global source.
// fused=1: write masked coco/cifar directly (no sim buffer, no mask pass).
__global__ __launch_bounds__(256) void k_gemm(const unsigned short* __restrict__ Fb,
                                              const unsigned short* __restrict__ Tb,
                                              const int* __restrict__ idx,
                                              float* __restrict__ sim,
                                              float* __restrict__ coco,
                                              float* __restrict__ cifar,
                                              int fused) {
    __shared__ unsigned short lA[128 * 64];   // 16 KB, [row][k] bf16, swizzled
    __shared__ unsigned short lB[128 * 64];   // 16 KB
    const int tid  = threadIdx.x;
    const int lane = tid & 63;
    const int wid  = tid >> 6;                // 0..3
    const int wm = wid >> 1, wn = wid & 1;    // 2x2 wave grid, 64x64 each
    const int brow = blockIdx.y * 128;
    const int bcol = blockIdx.x * 128;

    f32x4 acc[4][4] = {};

    for (int kt = 0; kt < ND / 64; ++kt) {
        if (kt) __syncthreads();
#pragma unroll
        for (int c = 0; c < 4; ++c) {
            const int ch  = c * 4 + wid;
            const int o   = ch * 1024 + lane * 16;   // linear LDS byte
            const int row = o >> 7;                  // 128 B per row
            const int kbu = (o & 127) ^ ((row & 7) << 4); // inverse-swizzled source
            const unsigned short* gA = Fb + ((size_t)(brow + row) << 9) + (kt << 5)*2 + (kbu >> 1);
            __builtin_amdgcn_global_load_lds(
                (const __attribute__((address_space(1))) unsigned int*)gA,
                (__attribute__((address_space(3))) unsigned int*)((char*)lA + ch * 1024),
                16, 0, 0);
            const unsigned short* gB = Tb + ((size_t)(bcol + row) << 9) + (kt << 5)*2 + (kbu >> 1);
            __builtin_amdgcn_global_load_lds(
                (const __attribute__((address_space(1))) unsigned int*)gB,
                (__attribute__((address_space(3))) unsigned int*)((char*)lB + ch * 1024),
                16, 0, 0);
        }
        __syncthreads();
#pragma unroll
        for (int ks = 0; ks < 2; ++ks) {
            u32x4 af[4], bfr[4];
#pragma unroll
            for (int mi = 0; mi < 4; ++mi) {
                const int row  = wm * 64 + mi * 16 + (lane & 15);
                const int kb   = ks * 64 + ((lane >> 4) << 4);
                const int addr = row * 128 + (kb ^ ((row & 7) << 4));
                af[mi] = *(const u32x4*)((const char*)lA + addr);
            }
#pragma unroll
            for (int ni = 0; ni < 4; ++ni) {
                const int row  = wn * 64 + ni * 16 + (lane & 15);
                const int kb   = ks * 64 + ((lane >> 4) << 4);
                const int addr = row * 128 + (kb ^ ((row & 7) << 4));
                bfr[ni] = *(const u32x4*)((const char*)lB + addr);
            }
#pragma unroll
            for (int mi = 0; mi < 4; ++mi)
#pragma unroll
                for (int ni = 0; ni < 4; ++ni)
                    asm("v_mfma_f32_16x16x32_bf16 %0, %1, %2, %0"
                        : "+v"(acc[mi][ni]) : "v"(af[mi]), "v"(bfr[ni]));
        }
    }
    asm volatile("s_nop 7\n\ts_nop 7\n\ts_nop 7" ::);   // MFMA->VALU hazard fence
    if (fused) {
#pragma unroll
        for (int mi = 0; mi < 4; ++mi) {
            const int rb = brow + wm * 64 + mi * 16 + ((lane >> 4) << 2);
            int fl[4];
#pragma unroll
            for (int rr = 0; rr < 4; ++rr) fl[rr] = (idx[rb + rr] == 1);
#pragma unroll
            for (int ni = 0; ni < 4; ++ni) {
                const int col = bcol + wn * 64 + ni * 16 + (lane & 15);
#pragma unroll
                for (int rr = 0; rr < 4; ++rr) {
                    const float s = acc[mi][ni][rr] * INV_TEMP;
                    const size_t o = (size_t)(rb + rr) * NC + col;
                    coco[o]  = fl[rr] ? 0.0f : s;
                    cifar[o] = fl[rr] ? s : 0.0f;
                }
            }
        }
    } else {
#pragma unroll
        for (int mi = 0; mi < 4; ++mi) {
            const int rb = brow + wm * 64 + mi * 16 + ((lane >> 4) << 2);
#pragma unroll
            for (int ni = 0; ni < 4; ++ni) {
                const int col = bcol + wn * 64 + ni * 16 + (lane & 15);
#pragma unroll
                for (int rr = 0; rr < 4; ++rr)
                    sim[(size_t)(rb + rr) * NC + col] = acc[mi][ni][rr] * INV_TEMP;
            }
        }
    }
}

// ---------------- per-row stats + ASL loss (one block per row) ----------------
// Fast ASL: sigmoid from shared exp, pow via exp2/log2 builtins.
// Optionally writes Ebf[i][c] = bf16(exp(sim)) for reuse by colsum/rowfinal.
__global__ __launch_bounds__(256) void k_stats(const float* __restrict__ pc,
                                               const float* __restrict__ pf,
                                               const int* __restrict__ idx,
                                               const float* __restrict__ tgt,
                                               unsigned short* __restrict__ Ebf,
                                               float* __restrict__ rowsum0,
                                               float* __restrict__ simdiag,
                                               float* __restrict__ Arow,
                                               float* __restrict__ Tsumv,
                                               float* __restrict__ rowmx,
                                               float* __restrict__ rowmn,
                                               float* __restrict__ scal) {
    const int i = blockIdx.x, tid = threadIdx.x;
    const float* srow = ((idx[i] == 1) ? pf : pc) + (size_t)i * NC;
    const float* trow = tgt + (size_t)i * NC;
    unsigned short* erow = Ebf ? (Ebf + (size_t)i * NC) : nullptr;
    float rs = 0.f, a = 0.f, ts = 0.f, ls = 0.f;
    float mx = -3.4e38f, mn = 3.4e38f;
    for (int c = tid * 4; c < NC; c += 1024) {
        const float s0 = srow[c], s1 = srow[c+1], s2 = srow[c+2], s3 = srow[c+3];
        const float4 t4 = *(const float4*)(trow + c);
        const float t0 = t4.x, t1 = t4.y, t2 = t4.z, t3 = t4.w;
        if ((unsigned)(i - c) < 4u)
            simdiag[i] = (i == c) ? s0 : ((i == c+1) ? s1 : ((i == c+2) ? s2 : s3));
        float e0, e1, e2, e3;
#define ASL(sv, tv, ev) { \
        ev = __expf(sv); \
        rs += ev; a += (tv) * ev; ts += (tv); \
        mx = fmaxf(mx, (sv)); mn = fminf(mn, (sv)); \
        const float inv = __builtin_amdgcn_rcpf(1.0f + ev); \
        const float xsp = ev * inv; \
        const float xsn = fminf(1.05f - xsp, 1.0f); \
        const float lp  = __logf(xsp); \
        const float ln  = __logf(xsn); \
        const float pt  = xsn + (tv) * (xsp - xsn); \
        const float g   = 4.0f - 3.0f * (tv); \
        const float pw  = __builtin_amdgcn_exp2f(g * __builtin_amdgcn_logf(1.0f - pt)); \
        ls += (ln + (tv) * (lp - ln)) * pw; }
        ASL(s0, t0, e0) ASL(s1, t1, e1) ASL(s2, t2, e2) ASL(s3, t3, e3)
#undef ASL
        if (erow) {
            uint2 w;
            w.x = (unsigned)f2bf(e0) | ((unsigned)f2bf(e1) << 16);
            w.y = (unsigned)f2bf(e2) | ((unsigned)f2bf(e3) << 16);
            *(uint2*)(erow + c) = w;
        }
    }
#pragma unroll
    for (int off = 1; off < 64; off <<= 1) {
        rs += __shfl_xor(rs, off);
        a  += __shfl_xor(a , off);
        ts += __shfl_xor(ts, off);
        ls += __shfl_xor(ls, off);
        mx = fmaxf(mx, __shfl_xor(mx, off));
        mn = fminf(mn, __shfl_xor(mn, off));
    }
    __shared__ float red[4][6];
    if ((tid & 63) == 0) {
        const int w = tid >> 6;
        red[w][0] = rs; red[w][1] = a; red[w][2] = ts;
        red[w][3] = ls; red[w][4] = mx; red[w][5] = mn;
    }
    __syncthreads();
    if (tid == 0) {
        rowsum0[i] = red[0][0] + red[1][0] + red[2][0] + red[3][0];
        Arow[i]    = red[0][1] + red[1][1] + red[2][1] + red[3][1];
        Tsumv[i]   = red[0][2] + red[1][2] + red[2][2] + red[3][2];
        atomicAdd(&scal[1], red[0][3] + red[1][3] + red[2][3] + red[3][3]);
        rowmx[i] = fmaxf(fmaxf(red[0][4], red[1][4]), fmaxf(red[2][4], red[3][4]));
        rowmn[i] = fminf(fminf(red[0][5], red[1][5]), fminf(red[2][5], red[3][5]));
    }
}

// ---------------- colsum from cached bf16 E:  colsum[j] = sum_i E[i][j]*r[i] ----------------
__global__ __launch_bounds__(256) void k_colsum_e(const unsigned short* __restrict__ Ebf,
                                                  const float* __restrict__ rv,
                                                  float* __restrict__ colsum) {
    const int j  = (blockIdx.x * 256 + threadIdx.x) * 4;   // gridx = NB/1024 = 4
    const int i0 = blockIdx.y * 64;                        // gridy = 64
    float a0 = 0.f, a1 = 0.f, a2 = 0.f, a3 = 0.f;
    for (int i = i0; i < i0 + 64; ++i) {
        const uint2 u = *(const uint2*)(Ebf + (size_t)i * NC + j);
        const float r = rv[i];
        a0 += bflo(u.x) * r;
        a1 += bfhi(u.x) * r;
        a2 += bflo(u.y) * r;
        a3 += bfhi(u.y) * r;
    }
    atomicAdd(&colsum[j    ], a0);
    atomicAdd(&colsum[j + 1], a1);
    atomicAdd(&colsum[j + 2], a2);
    atomicAdd(&colsum[j + 3], a3);
}

// ---------------- fallback colsum (no E buffer) ----------------
__global__ __launch_bounds__(256) void k_colsum(const float* __restrict__ pc,
                                                const float* __restrict__ pf,
                                                const int* __restrict__ idx,
                                                const float* __restrict__ rv,
                                                float* __restrict__ colsum) {
    const int j  = (blockIdx.x * 256 + threadIdx.x) * 4;   // gridx = NB/1024 = 4
    const int i0 = blockIdx.y * 32;                        // gridy = 128
    float a0 = 0.f, a1 = 0.f, a2 = 0.f, a3 = 0.f;
    for (int i = i0; i < i0 + 32; ++i) {
        const float* row = ((idx[i] == 1) ? pf : pc) + (size_t)i * NC;
        const float r = rv[i];
        a0 += __expf(row[j    ]) * r;
        a1 += __expf(row[j + 1]) * r;
        a2 += __expf(row[j + 2]) * r;
        a3 += __expf(row[j + 3]) * r;
    }
    atomicAdd(&colsum[j    ], a0);
    atomicAdd(&colsum[j + 1], a1);
    atomicAdd(&colsum[j + 2], a2);
    atomicAdd(&colsum[j + 3], a3);
}

// ---------------- per-iteration scalar update of r ----------------
__global__ __launch_bounds__(1024) void k_update(const float* __restrict__ simdiag,
                                                 float* __restrict__ colsum,
                                                 const float* __restrict__ rowsum0,
                                                 float* __restrict__ rv,
                                                 const float* __restrict__ scal) {
    __shared__ float red[1024];
    const int tid = threadIdx.x;
    float part = 0.f;
    float rl[4];
#pragma unroll
    for (int q = 0; q < 4; ++q) {
        const int i = tid + q * 1024;
        const float d  = fminf(simdiag[i] / colsum[i], 1.0f);
        const float rn = rv[i] * d;
        rl[q] = rn;
        part += rn * rowsum0[i];
        colsum[i] = 0.f;                    // reset for next iteration
    }
    red[tid] = part; __syncthreads();
    for (int s = 512; s > 0; s >>= 1) {
        if (tid < s) red[tid] += red[tid + s];
        __syncthreads();
    }
    const float sc = scal[0] / red[0];      // m / P.sum()
#pragma unroll
    for (int q = 0; q < 4; ++q) rv[tid + q * 1024] = rl[q] * sc;
}

// ---------------- logsumexp(P row) + multiclass accumulation, from bf16 E ----------------
__global__ __launch_bounds__(256) void k_rowfinal_e(const unsigned short* __restrict__ Ebf,
                                                    const float* __restrict__ rv,
                                                    const float* __restrict__ Arow,
                                                    const float* __restrict__ Tsumv,
                                                    const float* __restrict__ rowmx,
                                                    const float* __restrict__ rowmn,
                                                    float* __restrict__ scal) {
    const int i = blockIdx.x, tid = threadIdx.x;
    const float ri = rv[i];
    const unsigned short* erow = Ebf + (size_t)i * NC;
    // max of P row: ri>=0 -> ri*exp(rowmax); ri<0 -> ri*exp(rowmin).
    // (bf16 E can exceed exp(rowmax) by ~0.4%; logsumexp stays valid for any finite M)
    const float M = ri * __expf((ri >= 0.f) ? rowmx[i] : rowmn[i]);
    float se = 0.f;
    for (int c = tid * 8; c < NC; c += 2048) {
        const uint4 u = *(const uint4*)(erow + c);
        se += __expf(ri * bflo(u.x) - M);
        se += __expf(ri * bfhi(u.x) - M);
        se += __expf(ri * bflo(u.y) - M);
        se += __expf(ri * bfhi(u.y) - M);
        se += __expf(ri * bflo(u.z) - M);
        se += __expf(ri * bfhi(u.z) - M);
        se += __expf(ri * bflo(u.w) - M);
        se += __expf(ri * bfhi(u.w) - M);
    }
#pragma unroll
    for (int off = 1; off < 64; off <<= 1) se += __shfl_xor(se, off);
    __shared__ float red[4];
    if ((tid & 63) == 0) red[tid >> 6] = se;
    __syncthreads();
    if (tid == 0) {
        const float L = M + __logf(red[0] + red[1] + red[2] + red[3]);
        atomicAdd(&scal[2], Tsumv[i] * L - ri * Arow[i]);
    }
}

// ---------------- fallback rowfinal (no E buffer) ----------------
__global__ __launch_bounds__(256) void k_rowfinal(const float* __restrict__ pc,
                                                  const float* __restrict__ pf,
                                                  const int* __restrict__ idx,
                                                  const float* __restrict__ rv,
                                                  const float* __restrict__ Arow,
                                                  const float* __restrict__ Tsumv,
                                                  const float* __restrict__ rowmx,
                                                  const float* __restrict__ rowmn,
                                                  float* __restrict__ scal) {
    const int i = blockIdx.x, tid = threadIdx.x;
    const float ri = rv[i];
    const float* srow = ((idx[i] == 1) ? pf : pc) + (size_t)i * NC;
    const float M = ri * __expf((ri >= 0.f) ? rowmx[i] : rowmn[i]);
    float se = 0.f;
    for (int c = tid * 4; c < NC; c += 1024) {
        se += __expf(ri * __expf(srow[c    ]) - M);
        se += __expf(ri * __expf(srow[c + 1]) - M);
        se += __expf(ri * __expf(srow[c + 2]) - M);
        se += __expf(ri * __expf(srow[c + 3]) - M);
    }
#pragma unroll
    for (int off = 1; off < 64; off <<= 1) se += __shfl_xor(se, off);
    __shared__ float red[4];
    if ((tid & 63) == 0) red[tid >> 6] = se;
    __syncthreads();
    if (tid == 0) {
        const float L = M + __logf(red[0] + red[1] + red[2] + red[3]);
        atomicAdd(&scal[2], Tsumv[i] * L - ri * Arow[i]);
    }
}

// ---------------- final scalars ----------------
__global__ void k_scalars(const float* __restrict__ scal, float* __restrict__ out) {
    if (threadIdx.x == 0) {
        const float mc = scal[2] / (float)NB;
        const float ml = -scal[1];
        out[0] = mc + ml;
        out[1] = mc;
        out[2] = ml;
    }
}

// ---------------- masked sim outputs (fallback path; sim aliases cifar) ----------------
__global__ __launch_bounds__(256) void k_mask(const float* sim, const int* idx,
                                              float* coco, float* cifar) {
    const int i = blockIdx.y;
    const int c = blockIdx.x * 256 + threadIdx.x;
    const size_t o = (size_t)i * NC + c;
    const float s = sim[o];                 // read before any aliased write
    const bool isCifar = (idx[i] == 1);
    coco[o]  = isCifar ? 0.0f : s;
    cifar[o] = isCifar ? s : 0.0f;
}

extern "C" void kernel_launch(void* const* d_in, const int* in_sizes, int n_in,
                              void* d_out, int out_size, void* d_ws, size_t ws_size,
                              hipStream_t stream) {
    const float* F   = (const float*)d_in[0];   // [4096,512]
    const float* T   = (const float*)d_in[1];   // [8192,512]
    const float* tgt = (const float*)d_in[2];   // [4096,8192]
    const int*   idx = (const int*)d_in[3];     // [4096]

    float* out   = (float*)d_out;
    float* coco  = out + 3;
    float* cifar = coco + (size_t)NB * NC;

    const size_t FbBytes    = (size_t)NB * ND * 2;      // 4 MB
    const size_t TbBytes    = (size_t)NC * ND * 2;      // 8 MB
    const size_t EBytes     = (size_t)NB * NC * 2;      // 67 MB
    const size_t smallBytes = 10 * (size_t)NB * 4 + 1024;

    const bool fused = (d_ws != nullptr) &&
                       (ws_size >= FbBytes + TbBytes + smallBytes + 512);
    const bool hasE  = (d_ws != nullptr) &&
                       (ws_size >= FbBytes + TbBytes + EBytes + smallBytes + 512);
    unsigned short *Fb, *Tb, *Ebf = nullptr;
    float *sm, *sim;
    if (fused) {
        Fb  = (unsigned short*)d_ws;
        Tb  = (unsigned short*)((char*)d_ws + FbBytes);
        char* p = (char*)d_ws + FbBytes + TbBytes;
        if (hasE) { Ebf = (unsigned short*)p; p += EBytes; }
        sm  = (float*)p;
        sim = nullptr;
    } else {
        // sim lives in the cifar output slot; bf16 copies + small vectors in the
        // coco slot head (dead until k_mask, which runs last).
        sim = cifar;
        char* base = (char*)(((uintptr_t)(void*)coco + 255) & ~(uintptr_t)255);
        Fb  = (unsigned short*)base;
        Tb  = (unsigned short*)(base + FbBytes);
        sm  = (float*)(base + FbBytes + TbBytes);
    }
    float* colsum  = sm;
    float* rv      = sm + NB;
    float* rowsum0 = sm + 2 * NB;
    float* simdiag = sm + 3 * NB;
    float* Arow    = sm + 4 * NB;
    float* Tsumv   = sm + 5 * NB;
    float* rowmx   = sm + 6 * NB;
    float* rowmn   = sm + 7 * NB;
    float* scal    = sm + 8 * NB;

    const float* pc = fused ? coco  : sim;
    const float* pf = fused ? cifar : sim;

    k_init<<<1, 1024, 0, stream>>>(idx, colsum, rv, scal);
    k_cvt<<<(NB * ND / 4) / 256, 256, 0, stream>>>((const float4*)F, Fb, NB * ND / 4);
    k_cvt<<<(NC * ND / 4) / 256, 256, 0, stream>>>((const float4*)T, Tb, NC * ND / 4);
    k_gemm<<<dim3(NC / 128, NB / 128), 256, 0, stream>>>(Fb, Tb, idx, sim, coco, cifar,
                                                         fused ? 1 : 0);
    k_stats<<<NB, 256, 0, stream>>>(pc, pf, idx, tgt, Ebf, rowsum0, simdiag, Arow, Tsumv,
                                    rowmx, rowmn, scal);
    for (int it = 0; it < 5; ++it) {
        if (hasE)
            k_colsum_e<<<dim3(NB / 1024, 64), 256, 0, stream>>>(Ebf, rv, colsum);
        else
            k_colsum<<<dim3(NB / 1024, 128), 256, 0, stream>>>(pc, pf, idx, rv, colsum);
        k_update<<<1, 1024, 0, stream>>>(simdiag, colsum, rowsum0, rv, scal);
    }
    if (hasE)
        k_rowfinal_e<<<NB, 256, 0, stream>>>(Ebf, rv, Arow, Tsumv, rowmx, rowmn, scal);
    else
        k_rowfinal<<<NB, 256, 0, stream>>>(pc, pf, idx, rv, Arow, Tsumv, rowmx, rowmn, scal);
    k_scalars<<<1, 64, 0, stream>>>(scal, out);
    if (!fused) k_mask<<<dim3(NC / 256, NB), 256, 0, stream>>>(sim, idx, coco, cifar);
}